// Round 16
// baseline (76.935 us; speedup 1.0000x reference)
//
#include <hip/hip_runtime.h>

#define M_DIM 16384
#define N_DIM 1024
#define K_DIM 1024

typedef short v8s __attribute__((ext_vector_type(8)));
typedef float v4f __attribute__((ext_vector_type(4)));
typedef unsigned v2u __attribute__((ext_vector_type(2)));

__device__ __forceinline__ unsigned short f2bf(float f) {
  unsigned u = __float_as_uint(f);
  unsigned r = (u + 0x7FFFu + ((u >> 16) & 1u)) >> 16;
  return (unsigned short)r;
}

__device__ __forceinline__ void gload16(const void* g, void* l) {
  __builtin_amdgcn_global_load_lds(
      (const __attribute__((address_space(1))) void*)g,
      (__attribute__((address_space(3))) void*)l, 16, 0, 0);
}

// inline-asm ds_read_b128: invisible to SIInsertWaitcnts (no forced vmcnt
// drain against in-flight global_load_lds). offset is a string literal.
#define DSR(dst, addr, off) \
  asm volatile("ds_read_b128 %0, %1 offset:" off : "=v"(dst) : "v"(addr))

// order-preserving float<->uint key: k(a) < k(b) <=> a < b (finite floats)
__device__ __forceinline__ unsigned fkey(float f) {
  unsigned u = __float_as_uint(f);
  return (u & 0x80000000u) ? ~u : (u | 0x80000000u);
}
__device__ __forceinline__ float fdec(unsigned k) {
  unsigned u = (k & 0x80000000u) ? (k ^ 0x80000000u) : ~k;
  return __uint_as_float(u);
}

// ---------- fused prep: minmax + quantize in ONE kernel ----------
// 256 blocks x 256 threads; block b owns 4096 floats (1024 float4, coalesced
// stride-256 per thread). Phase 1: local minmax (values stay in VGPRs).
// Phase 2: device-scope atomicMax of fkey(max) and fkey(-min) (memset-0 is
// the identity for both); arrive on counter; t0 spins until all 256 blocks
// arrived (256 blocks <= 256 CUs -> all co-resident -> no deadlock).
// Phase 3: quantize own chunk from registers. Exact, order-independent.
__global__ void prep_kernel(const float* __restrict__ w,
                            unsigned short* __restrict__ wq,
                            unsigned* __restrict__ sync) {
  const int b = blockIdx.x, t = threadIdx.x;
  float4 v[4];
  float mx = -3.402823466e38f, mn = 3.402823466e38f;
  #pragma unroll
  for (int k = 0; k < 4; k++) {
    v[k] = *(const float4*)(w + (size_t)(b * 1024 + k * 256 + t) * 4);
    mx = fmaxf(fmaxf(mx, fmaxf(v[k].x, v[k].y)), fmaxf(v[k].z, v[k].w));
    mn = fminf(fminf(mn, fminf(v[k].x, v[k].y)), fminf(v[k].z, v[k].w));
  }
  #pragma unroll
  for (int o = 32; o > 0; o >>= 1) {
    mx = fmaxf(mx, __shfl_down(mx, o));
    mn = fminf(mn, __shfl_down(mn, o));
  }
  __shared__ float smx[4], smn[4];
  __shared__ float sab[2];
  const int lane = t & 63, wv = t >> 6;
  if (lane == 0) { smx[wv] = mx; smn[wv] = mn; }
  __syncthreads();
  if (t == 0) {
    mx = fmaxf(fmaxf(smx[0], smx[1]), fmaxf(smx[2], smx[3]));
    mn = fminf(fminf(smn[0], smn[1]), fminf(smn[2], smn[3]));
    atomicMax(&sync[0], fkey(mx));        // global max
    atomicMax(&sync[1], fkey(-mn));       // global min via max of -f
    __threadfence();
    atomicAdd(&sync[2], 1u);
    while (atomicAdd(&sync[2], 0u) < 256u) {}
    const float fmx = fdec(atomicAdd(&sync[0], 0u));
    const float fmn = -fdec(atomicAdd(&sync[1], 0u));
    sab[0] = fmx - fmn;                   // alpha
    sab[1] = fmn;                         // beta
  }
  __syncthreads();
  const float alpha = sab[0], beta = sab[1];
  #pragma unroll
  for (int k = 0; k < 4; k++) {
    float f[4] = {v[k].x, v[k].y, v[k].z, v[k].w};
    ushort4 o;
    unsigned short ov[4];
    #pragma unroll
    for (int j = 0; j < 4; j++) {
      // exact reference op sequence (fp32 divisions, rint = round-half-even)
      float s = (f[j] - beta) / alpha;
      float R = rintf(15.0f * s) / 15.0f;
      float q = alpha * R + beta;
      if (f[j] == 0.0f) q = 0.0f;
      ov[j] = f2bf(q);
    }
    o.x = ov[0]; o.y = ov[1]; o.z = ov[2]; o.w = ov[3];
    *(ushort4*)(wq + (size_t)(b * 1024 + k * 256 + t) * 4) = o;
  }
}

// ---------- stage 4 (round-8/15 proven, 66.7us total): fused 256x256 GEMM,
// A converted f32->bf16 in-kernel (no conv pass, no xbf traffic).
// 8 waves (2x4), K-halves of 32. PH0 {8 asm ds_read || issue 4 A-f32
// loads(h+2); BAR; lgkm0; 16 MFMA; BAR}, PH1 {4 asm ds_read; cvt A(h+1)->
// ds_write; 2 B gload_lds(h+2); BAR; lgkm0; 16 MFMA; vmcnt(6); BAR}.
// A-slots x2 ping-pong, B-slots x4 ring. LDS 96KB. Chunk-XOR swizzle.
__global__ __launch_bounds__(512, 2) void gemm_fused(
    const float* __restrict__ x, const unsigned short* __restrict__ wq,
    const float* __restrict__ bias, float* __restrict__ out) {
  __shared__ __attribute__((aligned(16))) unsigned short As[2][256][32];  // 32KB
  __shared__ __attribute__((aligned(16))) unsigned short Bs[4][256][32];  // 64KB

  const int tid = threadIdx.x;
  const int lane = tid & 63;
  const int wv = tid >> 6;     // 0..7
  const int wr = wv >> 2;      // 0..1  (M half: 128 rows)
  const int wc = wv & 3;       // 0..3  (N quarter: 64 cols)
  const int bm = blockIdx.x;   // 0..63
  const int bn = blockIdx.y;   // 0..3

  // B staging: wave wv owns rows [wv*32, wv*32+32); LDS dest linear, global
  // source chunk pre-swizzled by ((row>>1)&3).
  const int srow = wv * 32 + (lane >> 2);
  const int ssw = ((lane & 3) ^ ((lane >> 3) & 3)) * 8;
  const unsigned short* bS = wq + (size_t)(bn * 256 + srow) * K_DIM + ssw;

  // A staging (f32): lane covers row wv*32 + j*8 + (lane>>3), k (lane&7)*4..+3
  const float* aF = x + (size_t)(bm * 256 + wv * 32 + (lane >> 3)) * K_DIM + (lane & 7) * 4;

  // fragment read addressing (swizzled), LDS byte addresses
  const int frow = lane & 15;
  const int fsw = ((lane >> 4) ^ ((frow >> 1) & 3)) * 8;
  const unsigned ldsA0 =
      (unsigned)(unsigned long long)(__attribute__((address_space(3))) unsigned short*)&As[0][0][0];
  const unsigned ldsB0 =
      (unsigned)(unsigned long long)(__attribute__((address_space(3))) unsigned short*)&Bs[0][0][0];
  const unsigned aLane = ldsA0 + (unsigned)((wr * 128 + frow) * 32 + fsw) * 2u;
  const unsigned bLane = ldsB0 + (unsigned)((wc * 64 + frow) * 32 + fsw) * 2u;

  // A ds_write addr: element (r, k-chunk c) stored at c ^ ((r>>1)&3); for this
  // lane mapping (r>>1)&3 == (lane>>4)&3.
  const unsigned wA = ldsA0 +
      (unsigned)((wv * 32 + (lane >> 3)) * 64 +
                 ((((lane & 7) >> 1) ^ ((lane >> 4) & 3)) * 16) + ((lane & 7) & 1) * 8);

  v4f acc[8][4];
  #pragma unroll
  for (int m = 0; m < 8; m++)
    #pragma unroll
    for (int n = 0; n < 4; n++) acc[m][n] = (v4f)(0.0f);

  v8s af[4], bf[4];
  float4 ra0[4], ra1[4];

#define RA_LOAD(RA_, H2_) do { \
    _Pragma("unroll") \
    for (int j_ = 0; j_ < 4; j_++) \
      RA_[j_] = *(const float4*)(aF + (size_t)(H2_) * 32 + j_ * 8 * K_DIM); \
  } while (0)

#define CVTW(RA_, SL_) do { \
    _Pragma("unroll") \
    for (int j_ = 0; j_ < 4; j_++) { \
      v2u p_; \
      p_.x = (unsigned)f2bf(RA_[j_].x) | ((unsigned)f2bf(RA_[j_].y) << 16); \
      p_.y = (unsigned)f2bf(RA_[j_].z) | ((unsigned)f2bf(RA_[j_].w) << 16); \
      asm volatile("ds_write_b64 %0, %1" \
                   :: "v"(wA + (SL_) * 16384u + j_ * 512u), "v"(p_) : "memory"); \
    } \
  } while (0)

#define STAGE_B(H_, SL_) do { \
    gload16(bS + (size_t)(H_) * 32, &Bs[SL_][wv * 32][0]); \
    gload16(bS + (size_t)(H_) * 32 + 16 * K_DIM, &Bs[SL_][wv * 32 + 16][0]); \
  } while (0)

#define MM16(MH_) do { \
    _Pragma("unroll") \
    for (int i_ = 0; i_ < 4; i_++) \
      _Pragma("unroll") \
      for (int n_ = 0; n_ < 4; n_++) \
        acc[(MH_) * 4 + i_][n_] = __builtin_amdgcn_mfma_f32_16x16x32_bf16( \
            af[i_], bf[n_], acc[(MH_) * 4 + i_][n_], 0, 0, 0); \
  } while (0)

#define PH0(H_, AS_, BS_, RALD_, STG_) do { \
    const unsigned aP = aLane + (AS_) * 16384u; \
    const unsigned bP = bLane + (BS_) * 16384u; \
    DSR(af[0], aP, "0");    DSR(af[1], aP, "1024"); \
    DSR(af[2], aP, "2048"); DSR(af[3], aP, "3072"); \
    DSR(bf[0], bP, "0");    DSR(bf[1], bP, "1024"); \
    DSR(bf[2], bP, "2048"); DSR(bf[3], bP, "3072"); \
    if (STG_) RA_LOAD(RALD_, (H_) + 2); \
    __builtin_amdgcn_s_barrier(); \
    asm volatile("s_waitcnt lgkmcnt(0)" ::: "memory"); \
    __builtin_amdgcn_sched_barrier(0); \
    __builtin_amdgcn_s_setprio(1); \
    MM16(0); \
    __builtin_amdgcn_s_setprio(0); \
    __builtin_amdgcn_s_barrier(); \
  } while (0)

#define PH1(H_, AS_, BW_, RACV_, STG_, CVT_, GATE_) do { \
    const unsigned aP = aLane + (AS_) * 16384u + 4096u; \
    DSR(af[0], aP, "0");    DSR(af[1], aP, "1024"); \
    DSR(af[2], aP, "2048"); DSR(af[3], aP, "3072"); \
    if (CVT_) CVTW(RACV_, (AS_) ^ 1); \
    if (STG_) STAGE_B((H_) + 2, BW_); \
    __builtin_amdgcn_s_barrier(); \
    asm volatile("s_waitcnt lgkmcnt(0)" ::: "memory"); \
    __builtin_amdgcn_sched_barrier(0); \
    __builtin_amdgcn_s_setprio(1); \
    MM16(1); \
    __builtin_amdgcn_s_setprio(0); \
    asm volatile("s_waitcnt vmcnt(" GATE_ ")" ::: "memory"); \
    __builtin_amdgcn_s_barrier(); \
  } while (0)

#define KHALF(H_, AS_, BS_, BW_, RALD_, RACV_, STG_, CVT_, GATE_) do { \
    PH0(H_, AS_, BS_, RALD_, STG_); \
    PH1(H_, AS_, BW_, RACV_, STG_, CVT_, GATE_); \
  } while (0)

  // ---- prologue ----
  RA_LOAD(ra0, 0);            // A f32 for K-half 0 (4 loads)
  RA_LOAD(ra1, 1);            // A f32 for K-half 1 (4 loads)
  STAGE_B(0, 0);              // 2 gloads
  STAGE_B(1, 1);              // 2 gloads
  CVTW(ra0, 0);               // compiler waits exactly for ra0
  asm volatile("s_waitcnt vmcnt(2)" ::: "memory");  // B(0) landed, B(1) in flight
  asm volatile("s_waitcnt lgkmcnt(0)" ::: "memory");
  __builtin_amdgcn_s_barrier();

  // ---- main: 7 x 4 K-halves (h = 0..27) ----
  #pragma unroll 1
  for (int kh = 0; kh < 28; kh += 4) {
    KHALF(kh + 0, 0, 0, 2, ra0, ra1, 1, 1, "6");
    KHALF(kh + 1, 1, 1, 3, ra1, ra0, 1, 1, "6");
    KHALF(kh + 2, 0, 2, 0, ra0, ra1, 1, 1, "6");
    KHALF(kh + 3, 1, 3, 1, ra1, ra0, 1, 1, "6");
  }
  // ---- tail ----
  KHALF(28, 0, 0, 2, ra0, ra1, 1, 1, "6");
  KHALF(29, 1, 1, 3, ra1, ra0, 1, 1, "6");
  KHALF(30, 0, 2, 0, ra0, ra1, 0, 1, "0");  // cvt A(31)->slot1; drain for B(31)
  KHALF(31, 1, 3, 0, ra1, ra0, 0, 0, "0");

#undef KHALF
#undef PH0
#undef PH1
#undef MM16
#undef STAGE_B
#undef CVTW
#undef RA_LOAD

  // C-write: col = lane&15, row = (lane>>4)*4 + reg  [m89-verified]
  const int colbase = bn * 256 + wc * 64;
  const int rowbase = bm * 256 + wr * 128;
  #pragma unroll
  for (int n = 0; n < 4; n++) {
    const int col = colbase + n * 16 + (lane & 15);
    const float bv = bias[col];
    #pragma unroll
    for (int m = 0; m < 8; m++) {
      const int row0 = rowbase + m * 16 + (lane >> 4) * 4;
      #pragma unroll
      for (int r = 0; r < 4; r++)
        out[(size_t)(row0 + r) * N_DIM + col] = acc[m][n][r] + bv;
    }
  }
}

// ---------- fallback (ws too small): round-2 proven kernel ----------
__global__ __launch_bounds__(256) void gemm_kernel(
    const float* __restrict__ x, const unsigned short* __restrict__ wq,
    const float* __restrict__ bias, float* __restrict__ out) {
  __shared__ __attribute__((aligned(16))) unsigned short As[2][128][32];
  __shared__ __attribute__((aligned(16))) unsigned short Bs[2][128][32];

  const int tid = threadIdx.x;
  const int lane = tid & 63;
  const int wv = tid >> 6;
  const int wr = wv >> 1, wc = wv & 1;
  const int bm = blockIdx.x, bn = blockIdx.y;

  const int arow = tid >> 1;
  const int acol = (tid & 1) << 4;
  const float* aptr = x + (size_t)(bm * 128 + arow) * K_DIM + acol;
  const int fA = (arow >> 1) & 3;
  const int ac0 = (tid & 1) * 2;
  const int aw0 = ((ac0) ^ fA) * 8;
  const int aw1 = ((ac0 + 1) ^ fA) * 8;

  const int brow0 = wv * 32 + (lane >> 2);
  const int bsrcc = (lane & 3) ^ ((lane >> 3) & 3);
  const unsigned short* bptr0 = wq + (size_t)(bn * 128 + brow0) * K_DIM + bsrcc * 8;
  const unsigned short* bptr1 = bptr0 + (size_t)16 * K_DIM;

  v4f acc[4][4];
  #pragma unroll
  for (int i = 0; i < 4; i++)
    #pragma unroll
    for (int j = 0; j < 4; j++) acc[i][j] = (v4f)(0.0f);

  const int frow = lane & 15;
  const int fkc = lane >> 4;
  const int fsw = (fkc ^ ((frow >> 1) & 3)) * 8;

  float4 areg[4];
  #pragma unroll
  for (int j = 0; j < 4; j++) areg[j] = *(const float4*)(aptr + j * 4);

  {
    const float* f = (const float*)areg;
    union { v8s v; unsigned short u[8]; } cv0, cv1;
    #pragma unroll
    for (int i = 0; i < 8; i++) { cv0.u[i] = f2bf(f[i]); cv1.u[i] = f2bf(f[i + 8]); }
    *(v8s*)&As[0][arow][aw0] = cv0.v;
    *(v8s*)&As[0][arow][aw1] = cv1.v;
    gload16(bptr0, &Bs[0][wv * 32][0]);
    gload16(bptr1, &Bs[0][wv * 32 + 16][0]);
  }
  #pragma unroll
  for (int j = 0; j < 4; j++) areg[j] = *(const float4*)(aptr + 32 + j * 4);
  __syncthreads();

  for (int kt = 0; kt < K_DIM / 32; ++kt) {
    const int cur = kt & 1, nxt = cur ^ 1;
    if (kt + 1 < K_DIM / 32) {
      const float* f = (const float*)areg;
      union { v8s v; unsigned short u[8]; } cv0, cv1;
      #pragma unroll
      for (int i = 0; i < 8; i++) { cv0.u[i] = f2bf(f[i]); cv1.u[i] = f2bf(f[i + 8]); }
      *(v8s*)&As[nxt][arow][aw0] = cv0.v;
      *(v8s*)&As[nxt][arow][aw1] = cv1.v;
      gload16(bptr0 + (size_t)(kt + 1) * 32, &Bs[nxt][wv * 32][0]);
      gload16(bptr1 + (size_t)(kt + 1) * 32, &Bs[nxt][wv * 32 + 16][0]);
      if (kt + 2 < K_DIM / 32) {
        const float* ap = aptr + (kt + 2) * 32;
        #pragma unroll
        for (int j = 0; j < 4; j++) areg[j] = *(const float4*)(ap + j * 4);
      }
    }
    v8s af[4], bf[4];
    #pragma unroll
    for (int m = 0; m < 4; m++)
      af[m] = *(const v8s*)&As[cur][wr * 64 + m * 16 + frow][fsw];
    #pragma unroll
    for (int n = 0; n < 4; n++)
      bf[n] = *(const v8s*)&Bs[cur][wc * 64 + n * 16 + frow][fsw];
    #pragma unroll
    for (int m = 0; m < 4; m++)
      #pragma unroll
      for (int n = 0; n < 4; n++)
        acc[m][n] = __builtin_amdgcn_mfma_f32_16x16x32_bf16(af[m], bf[n], acc[m][n], 0, 0, 0);
    __syncthreads();
  }

  const int colbase = bn * 128 + wc * 64;
  const int rowbase = bm * 128 + wr * 64;
  #pragma unroll
  for (int n = 0; n < 4; n++) {
    const int col = colbase + n * 16 + (lane & 15);
    const float bv = bias[col];
    #pragma unroll
    for (int m = 0; m < 4; m++) {
      const int row0 = rowbase + m * 16 + (lane >> 4) * 4;
      #pragma unroll
      for (int r = 0; r < 4; r++)
        out[(size_t)(row0 + r) * N_DIM + col] = acc[m][n][r] + bv;
    }
  }
}

extern "C" void kernel_launch(void* const* d_in, const int* in_sizes, int n_in,
                              void* d_out, int out_size, void* d_ws, size_t ws_size,
                              hipStream_t stream) {
  const float* x = (const float*)d_in[0];      // 16384 x 1024
  const float* wt = (const float*)d_in[1];     // 1024 x 1024 (n, m)
  const float* bias = (const float*)d_in[2];   // 1024
  float* out = (float*)d_out;                  // 16384 x 1024

  // ws layout: [0,16) sync {maxkey, negminkey, counter, pad}; [4096, +2MB) wq
  unsigned* sync = (unsigned*)d_ws;
  unsigned short* wqbuf = (unsigned short*)((char*)d_ws + 4096);
  const size_t need = 4096 + 2ull * 1024 * 1024;

  hipMemsetAsync(d_ws, 0, 16, stream);
  prep_kernel<<<256, 256, 0, stream>>>(wt, wqbuf, sync);

  if (ws_size >= need) {
    dim3 grid(M_DIM / 256, N_DIM / 256);
    gemm_fused<<<grid, 512, 0, stream>>>(x, wqbuf, bias, out);
  } else {
    dim3 grid(M_DIM / 128, N_DIM / 128);
    gemm_kernel<<<grid, 256, 0, stream>>>(x, wqbuf, bias, out);
  }
}

// Round 17
// 64.818 us; speedup vs baseline: 1.1869x; 1.1869x over previous
//
#include <hip/hip_runtime.h>
#include <hip/hip_bf16.h>

#define M_DIM 16384
#define N_DIM 1024
#define K_DIM 1024

typedef short v8s __attribute__((ext_vector_type(8)));
typedef float v4f __attribute__((ext_vector_type(4)));
typedef unsigned v2u __attribute__((ext_vector_type(2)));

__device__ __forceinline__ unsigned short f2bf(float f) {
  unsigned u = __float_as_uint(f);
  unsigned r = (u + 0x7FFFu + ((u >> 16) & 1u)) >> 16;
  return (unsigned short)r;
}

// RTNE f32->bf16 via compiler intrinsic: pairs into v_cvt_pk_bf16_f32 (m240:
// scalar casts compile well; identical rounding to the f2bf bit-twiddle).
__device__ __forceinline__ unsigned short f2bf_hw(float f) {
  __hip_bfloat16 h = __float2bfloat16(f);
  return *reinterpret_cast<unsigned short*>(&h);
}

__device__ __forceinline__ void gload16(const void* g, void* l) {
  __builtin_amdgcn_global_load_lds(
      (const __attribute__((address_space(1))) void*)g,
      (__attribute__((address_space(3))) void*)l, 16, 0, 0);
}

// inline-asm ds_read_b128: invisible to SIInsertWaitcnts (no forced vmcnt
// drain against in-flight global_load_lds). offset is a string literal.
#define DSR(dst, addr, off) \
  asm volatile("ds_read_b128 %0, %1 offset:" off : "=v"(dst) : "v"(addr))

// ---------- stage 1/2: weight max/min (float4-vectorized) ----------
__global__ void wminmax_part(const float* __restrict__ w, float* __restrict__ part) {
  int tid = blockIdx.x * 256 + threadIdx.x;
  float mx = -3.402823466e38f, mn = 3.402823466e38f;
  for (int i = tid; i < N_DIM * K_DIM / 4; i += 256 * 256) {
    float4 v = *(const float4*)(w + i * 4);
    mx = fmaxf(fmaxf(mx, fmaxf(v.x, v.y)), fmaxf(v.z, v.w));
    mn = fminf(fminf(mn, fminf(v.x, v.y)), fminf(v.z, v.w));
  }
  #pragma unroll
  for (int o = 32; o > 0; o >>= 1) {
    mx = fmaxf(mx, __shfl_down(mx, o));
    mn = fminf(mn, __shfl_down(mn, o));
  }
  __shared__ float smx[4], smn[4];
  int lane = threadIdx.x & 63, wv = threadIdx.x >> 6;
  if (lane == 0) { smx[wv] = mx; smn[wv] = mn; }
  __syncthreads();
  if (threadIdx.x == 0) {
    mx = fmaxf(fmaxf(smx[0], smx[1]), fmaxf(smx[2], smx[3]));
    mn = fminf(fminf(smn[0], smn[1]), fminf(smn[2], smn[3]));
    part[blockIdx.x] = mx;
    part[256 + blockIdx.x] = mn;
  }
}

__global__ void wminmax_final(const float* __restrict__ part, float* __restrict__ mm) {
  float mx = part[threadIdx.x];
  float mn = part[256 + threadIdx.x];
  #pragma unroll
  for (int o = 32; o > 0; o >>= 1) {
    mx = fmaxf(mx, __shfl_down(mx, o));
    mn = fminf(mn, __shfl_down(mn, o));
  }
  __shared__ float smx[4], smn[4];
  int lane = threadIdx.x & 63, wv = threadIdx.x >> 6;
  if (lane == 0) { smx[wv] = mx; smn[wv] = mn; }
  __syncthreads();
  if (threadIdx.x == 0) {
    mm[0] = fmaxf(fmaxf(smx[0], smx[1]), fmaxf(smx[2], smx[3]));
    mm[1] = fminf(fminf(smn[0], smn[1]), fminf(smn[2], smn[3]));
  }
}

// ---------- stage 3: fake-quant weight -> bf16 ----------
__global__ void quant_kernel(const float* __restrict__ w, const float* __restrict__ mm,
                             unsigned short* __restrict__ wq) {
  const float mx = mm[0], mn = mm[1];
  const float alpha = mx - mn, beta = mn;
  int i = (blockIdx.x * 256 + threadIdx.x) * 4;
  float4 v = *(const float4*)(w + i);
  float f[4] = {v.x, v.y, v.z, v.w};
  ushort4 o;
  unsigned short ov[4];
  #pragma unroll
  for (int j = 0; j < 4; j++) {
    float s = (f[j] - beta) / alpha;
    float R = rintf(15.0f * s) / 15.0f;
    float q = alpha * R + beta;
    if (f[j] == 0.0f) q = 0.0f;
    ov[j] = f2bf(q);
  }
  o.x = ov[0]; o.y = ov[1]; o.z = ov[2]; o.w = ov[3];
  *(ushort4*)(wq + i) = o;
}

// ---------- stage 4 (round-8/15 proven structure): fused 256x256 GEMM,
// A converted f32->bf16 in-kernel via v_cvt_pk_bf16_f32 (this round's lever).
// 8 waves (2x4), K-halves of 32. PH0 {8 asm ds_read || issue 4 A-f32
// loads(h+2); BAR; lgkm0; 16 MFMA; BAR}, PH1 {4 asm ds_read; cvt A(h+1)->
// ds_write; 2 B gload_lds(h+2); BAR; lgkm0; 16 MFMA; vmcnt(6); BAR}.
// A-slots x2 ping-pong, B-slots x4 ring. LDS 96KB. Chunk-XOR swizzle.
__global__ __launch_bounds__(512, 2) void gemm_fused(
    const float* __restrict__ x, const unsigned short* __restrict__ wq,
    const float* __restrict__ bias, float* __restrict__ out) {
  __shared__ __attribute__((aligned(16))) unsigned short As[2][256][32];  // 32KB
  __shared__ __attribute__((aligned(16))) unsigned short Bs[4][256][32];  // 64KB

  const int tid = threadIdx.x;
  const int lane = tid & 63;
  const int wv = tid >> 6;     // 0..7
  const int wr = wv >> 2;      // 0..1  (M half: 128 rows)
  const int wc = wv & 3;       // 0..3  (N quarter: 64 cols)
  const int bm = blockIdx.x;   // 0..63
  const int bn = blockIdx.y;   // 0..3

  // B staging: wave wv owns rows [wv*32, wv*32+32); LDS dest linear, global
  // source chunk pre-swizzled by ((row>>1)&3).
  const int srow = wv * 32 + (lane >> 2);
  const int ssw = ((lane & 3) ^ ((lane >> 3) & 3)) * 8;
  const unsigned short* bS = wq + (size_t)(bn * 256 + srow) * K_DIM + ssw;

  // A staging (f32): lane covers row wv*32 + j*8 + (lane>>3), k (lane&7)*4..+3
  const float* aF = x + (size_t)(bm * 256 + wv * 32 + (lane >> 3)) * K_DIM + (lane & 7) * 4;

  // fragment read addressing (swizzled), LDS byte addresses
  const int frow = lane & 15;
  const int fsw = ((lane >> 4) ^ ((frow >> 1) & 3)) * 8;
  const unsigned ldsA0 =
      (unsigned)(unsigned long long)(__attribute__((address_space(3))) unsigned short*)&As[0][0][0];
  const unsigned ldsB0 =
      (unsigned)(unsigned long long)(__attribute__((address_space(3))) unsigned short*)&Bs[0][0][0];
  const unsigned aLane = ldsA0 + (unsigned)((wr * 128 + frow) * 32 + fsw) * 2u;
  const unsigned bLane = ldsB0 + (unsigned)((wc * 64 + frow) * 32 + fsw) * 2u;

  // A ds_write addr: element (r, k-chunk c) stored at c ^ ((r>>1)&3); for this
  // lane mapping (r>>1)&3 == (lane>>4)&3.
  const unsigned wA = ldsA0 +
      (unsigned)((wv * 32 + (lane >> 3)) * 64 +
                 ((((lane & 7) >> 1) ^ ((lane >> 4) & 3)) * 16) + ((lane & 7) & 1) * 8);

  v4f acc[8][4];
  #pragma unroll
  for (int m = 0; m < 8; m++)
    #pragma unroll
    for (int n = 0; n < 4; n++) acc[m][n] = (v4f)(0.0f);

  v8s af[4], bf[4];
  float4 ra0[4], ra1[4];

#define RA_LOAD(RA_, H2_) do { \
    _Pragma("unroll") \
    for (int j_ = 0; j_ < 4; j_++) \
      RA_[j_] = *(const float4*)(aF + (size_t)(H2_) * 32 + j_ * 8 * K_DIM); \
  } while (0)

#define CVTW(RA_, SL_) do { \
    _Pragma("unroll") \
    for (int j_ = 0; j_ < 4; j_++) { \
      v2u p_; \
      p_.x = (unsigned)f2bf_hw(RA_[j_].x) | ((unsigned)f2bf_hw(RA_[j_].y) << 16); \
      p_.y = (unsigned)f2bf_hw(RA_[j_].z) | ((unsigned)f2bf_hw(RA_[j_].w) << 16); \
      asm volatile("ds_write_b64 %0, %1" \
                   :: "v"(wA + (SL_) * 16384u + j_ * 512u), "v"(p_) : "memory"); \
    } \
  } while (0)

#define STAGE_B(H_, SL_) do { \
    gload16(bS + (size_t)(H_) * 32, &Bs[SL_][wv * 32][0]); \
    gload16(bS + (size_t)(H_) * 32 + 16 * K_DIM, &Bs[SL_][wv * 32 + 16][0]); \
  } while (0)

#define MM16(MH_) do { \
    _Pragma("unroll") \
    for (int i_ = 0; i_ < 4; i_++) \
      _Pragma("unroll") \
      for (int n_ = 0; n_ < 4; n_++) \
        acc[(MH_) * 4 + i_][n_] = __builtin_amdgcn_mfma_f32_16x16x32_bf16( \
            af[i_], bf[n_], acc[(MH_) * 4 + i_][n_], 0, 0, 0); \
  } while (0)

#define PH0(H_, AS_, BS_, RALD_, STG_) do { \
    const unsigned aP = aLane + (AS_) * 16384u; \
    const unsigned bP = bLane + (BS_) * 16384u; \
    DSR(af[0], aP, "0");    DSR(af[1], aP, "1024"); \
    DSR(af[2], aP, "2048"); DSR(af[3], aP, "3072"); \
    DSR(bf[0], bP, "0");    DSR(bf[1], bP, "1024"); \
    DSR(bf[2], bP, "2048"); DSR(bf[3], bP, "3072"); \
    if (STG_) RA_LOAD(RALD_, (H_) + 2); \
    __builtin_amdgcn_s_barrier(); \
    asm volatile("s_waitcnt lgkmcnt(0)" ::: "memory"); \
    __builtin_amdgcn_sched_barrier(0); \
    __builtin_amdgcn_s_setprio(1); \
    MM16(0); \
    __builtin_amdgcn_s_setprio(0); \
    __builtin_amdgcn_s_barrier(); \
  } while (0)

#define PH1(H_, AS_, BW_, RACV_, STG_, CVT_, GATE_) do { \
    const unsigned aP = aLane + (AS_) * 16384u + 4096u; \
    DSR(af[0], aP, "0");    DSR(af[1], aP, "1024"); \
    DSR(af[2], aP, "2048"); DSR(af[3], aP, "3072"); \
    if (CVT_) CVTW(RACV_, (AS_) ^ 1); \
    if (STG_) STAGE_B((H_) + 2, BW_); \
    __builtin_amdgcn_s_barrier(); \
    asm volatile("s_waitcnt lgkmcnt(0)" ::: "memory"); \
    __builtin_amdgcn_sched_barrier(0); \
    __builtin_amdgcn_s_setprio(1); \
    MM16(1); \
    __builtin_amdgcn_s_setprio(0); \
    asm volatile("s_waitcnt vmcnt(" GATE_ ")" ::: "memory"); \
    __builtin_amdgcn_s_barrier(); \
  } while (0)

#define KHALF(H_, AS_, BS_, BW_, RALD_, RACV_, STG_, CVT_, GATE_) do { \
    PH0(H_, AS_, BS_, RALD_, STG_); \
    PH1(H_, AS_, BW_, RACV_, STG_, CVT_, GATE_); \
  } while (0)

  // ---- prologue ----
  RA_LOAD(ra0, 0);            // A f32 for K-half 0 (4 loads)
  RA_LOAD(ra1, 1);            // A f32 for K-half 1 (4 loads)
  STAGE_B(0, 0);              // 2 gloads
  STAGE_B(1, 1);              // 2 gloads
  CVTW(ra0, 0);               // compiler waits exactly for ra0
  asm volatile("s_waitcnt vmcnt(2)" ::: "memory");  // B(0) landed, B(1) in flight
  asm volatile("s_waitcnt lgkmcnt(0)" ::: "memory");
  __builtin_amdgcn_s_barrier();

  // ---- main: 7 x 4 K-halves (h = 0..27) ----
  #pragma unroll 1
  for (int kh = 0; kh < 28; kh += 4) {
    KHALF(kh + 0, 0, 0, 2, ra0, ra1, 1, 1, "6");
    KHALF(kh + 1, 1, 1, 3, ra1, ra0, 1, 1, "6");
    KHALF(kh + 2, 0, 2, 0, ra0, ra1, 1, 1, "6");
    KHALF(kh + 3, 1, 3, 1, ra1, ra0, 1, 1, "6");
  }
  // ---- tail ----
  KHALF(28, 0, 0, 2, ra0, ra1, 1, 1, "6");
  KHALF(29, 1, 1, 3, ra1, ra0, 1, 1, "6");
  KHALF(30, 0, 2, 0, ra0, ra1, 0, 1, "0");  // cvt A(31)->slot1; drain for B(31)
  KHALF(31, 1, 3, 0, ra1, ra0, 0, 0, "0");

#undef KHALF
#undef PH0
#undef PH1
#undef MM16
#undef STAGE_B
#undef CVTW
#undef RA_LOAD

  // C-write: col = lane&15, row = (lane>>4)*4 + reg  [m89-verified]
  const int colbase = bn * 256 + wc * 64;
  const int rowbase = bm * 256 + wr * 128;
  #pragma unroll
  for (int n = 0; n < 4; n++) {
    const int col = colbase + n * 16 + (lane & 15);
    const float bv = bias[col];
    #pragma unroll
    for (int m = 0; m < 8; m++) {
      const int row0 = rowbase + m * 16 + (lane >> 4) * 4;
      #pragma unroll
      for (int r = 0; r < 4; r++)
        out[(size_t)(row0 + r) * N_DIM + col] = acc[m][n][r] + bv;
    }
  }
}

// ---------- fallback (ws too small): round-2 proven kernel ----------
__global__ __launch_bounds__(256) void gemm_kernel(
    const float* __restrict__ x, const unsigned short* __restrict__ wq,
    const float* __restrict__ bias, float* __restrict__ out) {
  __shared__ __attribute__((aligned(16))) unsigned short As[2][128][32];
  __shared__ __attribute__((aligned(16))) unsigned short Bs[2][128][32];

  const int tid = threadIdx.x;
  const int lane = tid & 63;
  const int wv = tid >> 6;
  const int wr = wv >> 1, wc = wv & 1;
  const int bm = blockIdx.x, bn = blockIdx.y;

  const int arow = tid >> 1;
  const int acol = (tid & 1) << 4;
  const float* aptr = x + (size_t)(bm * 128 + arow) * K_DIM + acol;
  const int fA = (arow >> 1) & 3;
  const int ac0 = (tid & 1) * 2;
  const int aw0 = ((ac0) ^ fA) * 8;
  const int aw1 = ((ac0 + 1) ^ fA) * 8;

  const int brow0 = wv * 32 + (lane >> 2);
  const int bsrcc = (lane & 3) ^ ((lane >> 3) & 3);
  const unsigned short* bptr0 = wq + (size_t)(bn * 128 + brow0) * K_DIM + bsrcc * 8;
  const unsigned short* bptr1 = bptr0 + (size_t)16 * K_DIM;

  v4f acc[4][4];
  #pragma unroll
  for (int i = 0; i < 4; i++)
    #pragma unroll
    for (int j = 0; j < 4; j++) acc[i][j] = (v4f)(0.0f);

  const int frow = lane & 15;
  const int fkc = lane >> 4;
  const int fsw = (fkc ^ ((frow >> 1) & 3)) * 8;

  float4 areg[4];
  #pragma unroll
  for (int j = 0; j < 4; j++) areg[j] = *(const float4*)(aptr + j * 4);

  {
    const float* f = (const float*)areg;
    union { v8s v; unsigned short u[8]; } cv0, cv1;
    #pragma unroll
    for (int i = 0; i < 8; i++) { cv0.u[i] = f2bf(f[i]); cv1.u[i] = f2bf(f[i + 8]); }
    *(v8s*)&As[0][arow][aw0] = cv0.v;
    *(v8s*)&As[0][arow][aw1] = cv1.v;
    gload16(bptr0, &Bs[0][wv * 32][0]);
    gload16(bptr1, &Bs[0][wv * 32 + 16][0]);
  }
  #pragma unroll
  for (int j = 0; j < 4; j++) areg[j] = *(const float4*)(aptr + 32 + j * 4);
  __syncthreads();

  for (int kt = 0; kt < K_DIM / 32; ++kt) {
    const int cur = kt & 1, nxt = cur ^ 1;
    if (kt + 1 < K_DIM / 32) {
      const float* f = (const float*)areg;
      union { v8s v; unsigned short u[8]; } cv0, cv1;
      #pragma unroll
      for (int i = 0; i < 8; i++) { cv0.u[i] = f2bf(f[i]); cv1.u[i] = f2bf(f[i + 8]); }
      *(v8s*)&As[nxt][arow][aw0] = cv0.v;
      *(v8s*)&As[nxt][arow][aw1] = cv1.v;
      gload16(bptr0 + (size_t)(kt + 1) * 32, &Bs[nxt][wv * 32][0]);
      gload16(bptr1 + (size_t)(kt + 1) * 32, &Bs[nxt][wv * 32 + 16][0]);
      if (kt + 2 < K_DIM / 32) {
        const float* ap = aptr + (kt + 2) * 32;
        #pragma unroll
        for (int j = 0; j < 4; j++) areg[j] = *(const float4*)(ap + j * 4);
      }
    }
    v8s af[4], bf[4];
    #pragma unroll
    for (int m = 0; m < 4; m++)
      af[m] = *(const v8s*)&As[cur][wr * 64 + m * 16 + frow][fsw];
    #pragma unroll
    for (int n = 0; n < 4; n++)
      bf[n] = *(const v8s*)&Bs[cur][wc * 64 + n * 16 + frow][fsw];
    #pragma unroll
    for (int m = 0; m < 4; m++)
      #pragma unroll
      for (int n = 0; n < 4; n++)
        acc[m][n] = __builtin_amdgcn_mfma_f32_16x16x32_bf16(af[m], bf[n], acc[m][n], 0, 0, 0);
    __syncthreads();
  }

  const int colbase = bn * 128 + wc * 64;
  const int rowbase = bm * 128 + wr * 64;
  #pragma unroll
  for (int n = 0; n < 4; n++) {
    const int col = colbase + n * 16 + (lane & 15);
    const float bv = bias[col];
    #pragma unroll
    for (int m = 0; m < 4; m++) {
      const int row0 = rowbase + m * 16 + (lane >> 4) * 4;
      #pragma unroll
      for (int r = 0; r < 4; r++)
        out[(size_t)(row0 + r) * N_DIM + col] = acc[m][n][r] + bv;
    }
  }
}

extern "C" void kernel_launch(void* const* d_in, const int* in_sizes, int n_in,
                              void* d_out, int out_size, void* d_ws, size_t ws_size,
                              hipStream_t stream) {
  const float* x = (const float*)d_in[0];      // 16384 x 1024
  const float* wt = (const float*)d_in[1];     // 1024 x 1024 (n, m)
  const float* bias = (const float*)d_in[2];   // 1024
  float* out = (float*)d_out;                  // 16384 x 1024

  float* part = (float*)d_ws;
  float* mm = part + 512;
  unsigned short* wqbuf = (unsigned short*)((char*)d_ws + 4096);
  const size_t need = 4096 + 2ull * 1024 * 1024;

  wminmax_part<<<256, 256, 0, stream>>>(wt, part);
  wminmax_final<<<1, 256, 0, stream>>>(part, mm);
  quant_kernel<<<1024, 256, 0, stream>>>(wt, mm, wqbuf);

  if (ws_size >= need) {
    dim3 grid(M_DIM / 256, N_DIM / 256);
    gemm_fused<<<grid, 512, 0, stream>>>(x, wqbuf, bias, out);
  } else {
    dim3 grid(M_DIM / 128, N_DIM / 128);
    gemm_kernel<<<grid, 256, 0, stream>>>(x, wqbuf, bias, out);
  }
}

// Round 18
// 63.780 us; speedup vs baseline: 1.2063x; 1.0163x over previous
//
#include <hip/hip_runtime.h>
#include <hip/hip_bf16.h>

#define M_DIM 16384
#define N_DIM 1024
#define K_DIM 1024

typedef short v8s __attribute__((ext_vector_type(8)));
typedef float v4f __attribute__((ext_vector_type(4)));
typedef unsigned v2u __attribute__((ext_vector_type(2)));

__device__ __forceinline__ unsigned short f2bf(float f) {
  unsigned u = __float_as_uint(f);
  unsigned r = (u + 0x7FFFu + ((u >> 16) & 1u)) >> 16;
  return (unsigned short)r;
}

// RTNE f32->bf16 via compiler intrinsic: pairs into v_cvt_pk_bf16_f32
// (proven round 17: -2us, identical rounding to the bit-twiddle).
__device__ __forceinline__ unsigned short f2bf_hw(float f) {
  __hip_bfloat16 h = __float2bfloat16(f);
  return *reinterpret_cast<unsigned short*>(&h);
}

__device__ __forceinline__ void gload16(const void* g, void* l) {
  __builtin_amdgcn_global_load_lds(
      (const __attribute__((address_space(1))) void*)g,
      (__attribute__((address_space(3))) void*)l, 16, 0, 0);
}

// inline-asm ds_read_b128: invisible to SIInsertWaitcnts (no forced vmcnt
// drain against in-flight global_load_lds). offset is a string literal.
#define DSR(dst, addr, off) \
  asm volatile("ds_read_b128 %0, %1 offset:" off : "=v"(dst) : "v"(addr))

// ---------- stage 1/2: weight max/min (float4-vectorized) ----------
__global__ void wminmax_part(const float* __restrict__ w, float* __restrict__ part) {
  int tid = blockIdx.x * 256 + threadIdx.x;
  float mx = -3.402823466e38f, mn = 3.402823466e38f;
  for (int i = tid; i < N_DIM * K_DIM / 4; i += 256 * 256) {
    float4 v = *(const float4*)(w + i * 4);
    mx = fmaxf(fmaxf(mx, fmaxf(v.x, v.y)), fmaxf(v.z, v.w));
    mn = fminf(fminf(mn, fminf(v.x, v.y)), fminf(v.z, v.w));
  }
  #pragma unroll
  for (int o = 32; o > 0; o >>= 1) {
    mx = fmaxf(mx, __shfl_down(mx, o));
    mn = fminf(mn, __shfl_down(mn, o));
  }
  __shared__ float smx[4], smn[4];
  int lane = threadIdx.x & 63, wv = threadIdx.x >> 6;
  if (lane == 0) { smx[wv] = mx; smn[wv] = mn; }
  __syncthreads();
  if (threadIdx.x == 0) {
    mx = fmaxf(fmaxf(smx[0], smx[1]), fmaxf(smx[2], smx[3]));
    mn = fminf(fminf(smn[0], smn[1]), fminf(smn[2], smn[3]));
    part[blockIdx.x] = mx;
    part[256 + blockIdx.x] = mn;
  }
}

__global__ void wminmax_final(const float* __restrict__ part, float* __restrict__ mm) {
  float mx = part[threadIdx.x];
  float mn = part[256 + threadIdx.x];
  #pragma unroll
  for (int o = 32; o > 0; o >>= 1) {
    mx = fmaxf(mx, __shfl_down(mx, o));
    mn = fminf(mn, __shfl_down(mn, o));
  }
  __shared__ float smx[4], smn[4];
  int lane = threadIdx.x & 63, wv = threadIdx.x >> 6;
  if (lane == 0) { smx[wv] = mx; smn[wv] = mn; }
  __syncthreads();
  if (threadIdx.x == 0) {
    mm[0] = fmaxf(fmaxf(smx[0], smx[1]), fmaxf(smx[2], smx[3]));
    mm[1] = fminf(fminf(smn[0], smn[1]), fminf(smn[2], smn[3]));
  }
}

// ---------- stage 3: fake-quant weight -> bf16 ----------
__global__ void quant_kernel(const float* __restrict__ w, const float* __restrict__ mm,
                             unsigned short* __restrict__ wq) {
  const float mx = mm[0], mn = mm[1];
  const float alpha = mx - mn, beta = mn;
  int i = (blockIdx.x * 256 + threadIdx.x) * 4;
  float4 v = *(const float4*)(w + i);
  float f[4] = {v.x, v.y, v.z, v.w};
  ushort4 o;
  unsigned short ov[4];
  #pragma unroll
  for (int j = 0; j < 4; j++) {
    float s = (f[j] - beta) / alpha;
    float R = rintf(15.0f * s) / 15.0f;
    float q = alpha * R + beta;
    if (f[j] == 0.0f) q = 0.0f;
    ov[j] = f2bf(q);
  }
  o.x = ov[0]; o.y = ov[1]; o.z = ov[2]; o.w = ov[3];
  *(ushort4*)(wq + i) = o;
}

// ---------- stage 4: fused 256x256 GEMM (round-17 proven main loop) +
// NEW: LDS-transposed fully-coalesced epilogue (this round's lever).
__global__ __launch_bounds__(512, 2) void gemm_fused(
    const float* __restrict__ x, const unsigned short* __restrict__ wq,
    const float* __restrict__ bias, float* __restrict__ out) {
  __shared__ __attribute__((aligned(16))) unsigned short As[2][256][32];  // 32KB
  __shared__ __attribute__((aligned(16))) unsigned short Bs[4][256][32];  // 64KB

  const int tid = threadIdx.x;
  const int lane = tid & 63;
  const int wv = tid >> 6;     // 0..7
  const int wr = wv >> 2;      // 0..1  (M half: 128 rows)
  const int wc = wv & 3;       // 0..3  (N quarter: 64 cols)
  const int bm = blockIdx.x;   // 0..63
  const int bn = blockIdx.y;   // 0..3

  // B staging: wave wv owns rows [wv*32, wv*32+32); LDS dest linear, global
  // source chunk pre-swizzled by ((row>>1)&3).
  const int srow = wv * 32 + (lane >> 2);
  const int ssw = ((lane & 3) ^ ((lane >> 3) & 3)) * 8;
  const unsigned short* bS = wq + (size_t)(bn * 256 + srow) * K_DIM + ssw;

  // A staging (f32): lane covers row wv*32 + j*8 + (lane>>3), k (lane&7)*4..+3
  const float* aF = x + (size_t)(bm * 256 + wv * 32 + (lane >> 3)) * K_DIM + (lane & 7) * 4;

  // fragment read addressing (swizzled), LDS byte addresses
  const int frow = lane & 15;
  const int fsw = ((lane >> 4) ^ ((frow >> 1) & 3)) * 8;
  const unsigned ldsA0 =
      (unsigned)(unsigned long long)(__attribute__((address_space(3))) unsigned short*)&As[0][0][0];
  const unsigned ldsB0 =
      (unsigned)(unsigned long long)(__attribute__((address_space(3))) unsigned short*)&Bs[0][0][0];
  const unsigned aLane = ldsA0 + (unsigned)((wr * 128 + frow) * 32 + fsw) * 2u;
  const unsigned bLane = ldsB0 + (unsigned)((wc * 64 + frow) * 32 + fsw) * 2u;

  // A ds_write addr: element (r, k-chunk c) stored at c ^ ((r>>1)&3); for this
  // lane mapping (r>>1)&3 == (lane>>4)&3.
  const unsigned wA = ldsA0 +
      (unsigned)((wv * 32 + (lane >> 3)) * 64 +
                 ((((lane & 7) >> 1) ^ ((lane >> 4) & 3)) * 16) + ((lane & 7) & 1) * 8);

  v4f acc[8][4];
  #pragma unroll
  for (int m = 0; m < 8; m++)
    #pragma unroll
    for (int n = 0; n < 4; n++) acc[m][n] = (v4f)(0.0f);

  v8s af[4], bf[4];
  float4 ra0[4], ra1[4];

#define RA_LOAD(RA_, H2_) do { \
    _Pragma("unroll") \
    for (int j_ = 0; j_ < 4; j_++) \
      RA_[j_] = *(const float4*)(aF + (size_t)(H2_) * 32 + j_ * 8 * K_DIM); \
  } while (0)

#define CVTW(RA_, SL_) do { \
    _Pragma("unroll") \
    for (int j_ = 0; j_ < 4; j_++) { \
      v2u p_; \
      p_.x = (unsigned)f2bf_hw(RA_[j_].x) | ((unsigned)f2bf_hw(RA_[j_].y) << 16); \
      p_.y = (unsigned)f2bf_hw(RA_[j_].z) | ((unsigned)f2bf_hw(RA_[j_].w) << 16); \
      asm volatile("ds_write_b64 %0, %1" \
                   :: "v"(wA + (SL_) * 16384u + j_ * 512u), "v"(p_) : "memory"); \
    } \
  } while (0)

#define STAGE_B(H_, SL_) do { \
    gload16(bS + (size_t)(H_) * 32, &Bs[SL_][wv * 32][0]); \
    gload16(bS + (size_t)(H_) * 32 + 16 * K_DIM, &Bs[SL_][wv * 32 + 16][0]); \
  } while (0)

#define MM16(MH_) do { \
    _Pragma("unroll") \
    for (int i_ = 0; i_ < 4; i_++) \
      _Pragma("unroll") \
      for (int n_ = 0; n_ < 4; n_++) \
        acc[(MH_) * 4 + i_][n_] = __builtin_amdgcn_mfma_f32_16x16x32_bf16( \
            af[i_], bf[n_], acc[(MH_) * 4 + i_][n_], 0, 0, 0); \
  } while (0)

#define PH0(H_, AS_, BS_, RALD_, STG_) do { \
    const unsigned aP = aLane + (AS_) * 16384u; \
    const unsigned bP = bLane + (BS_) * 16384u; \
    DSR(af[0], aP, "0");    DSR(af[1], aP, "1024"); \
    DSR(af[2], aP, "2048"); DSR(af[3], aP, "3072"); \
    DSR(bf[0], bP, "0");    DSR(bf[1], bP, "1024"); \
    DSR(bf[2], bP, "2048"); DSR(bf[3], bP, "3072"); \
    if (STG_) RA_LOAD(RALD_, (H_) + 2); \
    __builtin_amdgcn_s_barrier(); \
    asm volatile("s_waitcnt lgkmcnt(0)" ::: "memory"); \
    __builtin_amdgcn_sched_barrier(0); \
    __builtin_amdgcn_s_setprio(1); \
    MM16(0); \
    __builtin_amdgcn_s_setprio(0); \
    __builtin_amdgcn_s_barrier(); \
  } while (0)

#define PH1(H_, AS_, BW_, RACV_, STG_, CVT_, GATE_) do { \
    const unsigned aP = aLane + (AS_) * 16384u + 4096u; \
    DSR(af[0], aP, "0");    DSR(af[1], aP, "1024"); \
    DSR(af[2], aP, "2048"); DSR(af[3], aP, "3072"); \
    if (CVT_) CVTW(RACV_, (AS_) ^ 1); \
    if (STG_) STAGE_B((H_) + 2, BW_); \
    __builtin_amdgcn_s_barrier(); \
    asm volatile("s_waitcnt lgkmcnt(0)" ::: "memory"); \
    __builtin_amdgcn_sched_barrier(0); \
    __builtin_amdgcn_s_setprio(1); \
    MM16(1); \
    __builtin_amdgcn_s_setprio(0); \
    asm volatile("s_waitcnt vmcnt(" GATE_ ")" ::: "memory"); \
    __builtin_amdgcn_s_barrier(); \
  } while (0)

#define KHALF(H_, AS_, BS_, BW_, RALD_, RACV_, STG_, CVT_, GATE_) do { \
    PH0(H_, AS_, BS_, RALD_, STG_); \
    PH1(H_, AS_, BW_, RACV_, STG_, CVT_, GATE_); \
  } while (0)

  // ---- prologue ----
  RA_LOAD(ra0, 0);
  RA_LOAD(ra1, 1);
  STAGE_B(0, 0);
  STAGE_B(1, 1);
  CVTW(ra0, 0);
  asm volatile("s_waitcnt vmcnt(2)" ::: "memory");
  asm volatile("s_waitcnt lgkmcnt(0)" ::: "memory");
  __builtin_amdgcn_s_barrier();

  // ---- main: 7 x 4 K-halves (h = 0..27) ----
  #pragma unroll 1
  for (int kh = 0; kh < 28; kh += 4) {
    KHALF(kh + 0, 0, 0, 2, ra0, ra1, 1, 1, "6");
    KHALF(kh + 1, 1, 1, 3, ra1, ra0, 1, 1, "6");
    KHALF(kh + 2, 0, 2, 0, ra0, ra1, 1, 1, "6");
    KHALF(kh + 3, 1, 3, 1, ra1, ra0, 1, 1, "6");
  }
  // ---- tail ----
  KHALF(28, 0, 0, 2, ra0, ra1, 1, 1, "6");
  KHALF(29, 1, 1, 3, ra1, ra0, 1, 1, "6");
  KHALF(30, 0, 2, 0, ra0, ra1, 0, 1, "0");
  KHALF(31, 1, 3, 0, ra1, ra0, 0, 0, "0");

#undef KHALF
#undef PH0
#undef PH1
#undef MM16
#undef STAGE_B
#undef CVTW
#undef RA_LOAD

  // ---- epilogue: LDS-transposed fully-coalesced C-write ----
  // After the final barrier all LDS traffic is drained; reuse As as 8 private
  // 4KB wave tiles (16 rows x 64 f32). 16B granules XOR-swizzled by row
  // (g ^= R&15): writes are <=2-way (free), b128 reads spread evenly.
  // No block barriers needed: each wave uses only its own region, and a wave
  // executes its write burst before its read burst (lockstep); compiler
  // inserts the lgkm waits for the C++ LDS accesses.
  {
    float* eb = (float*)(&As[0][0][0]) + wv * (16 * 64);
    const int colbase = bn * 256 + wc * 64;
    const int rowbase = bm * 256 + wr * 128;
    float bv[4];
    #pragma unroll
    for (int n = 0; n < 4; n++) bv[n] = bias[colbase + n * 16 + (lane & 15)];
    const int er = lane >> 4;       // write-side row group
    const int ec = lane & 15;       // write-side col-in-16
    const int rr = lane >> 2;       // read-side row (0..15)
    const int q  = lane & 3;        // read-side 16B piece within 64B segment
    #pragma unroll
    for (int m = 0; m < 8; m++) {
      #pragma unroll
      for (int n = 0; n < 4; n++) {
        #pragma unroll
        for (int r = 0; r < 4; r++) {
          const int R = er * 4 + r;
          const int cn = n * 16 + ec;
          const int g = cn >> 2;
          eb[R * 64 + ((g ^ (R & 15)) << 2) + (cn & 3)] = acc[m][n][r] + bv[n];
        }
      }
      float* orow = out + (size_t)(rowbase + m * 16 + rr) * N_DIM + colbase;
      #pragma unroll
      for (int j = 0; j < 4; j++) {
        const int g = j * 4 + q;
        v4f v = *(v4f*)&eb[rr * 64 + ((g ^ (rr & 15)) << 2)];
        *(v4f*)&orow[j * 16 + q * 4] = v;
      }
    }
  }
}

// ---------- fallback (ws too small): round-2 proven kernel ----------
__global__ __launch_bounds__(256) void gemm_kernel(
    const float* __restrict__ x, const unsigned short* __restrict__ wq,
    const float* __restrict__ bias, float* __restrict__ out) {
  __shared__ __attribute__((aligned(16))) unsigned short As[2][128][32];
  __shared__ __attribute__((aligned(16))) unsigned short Bs[2][128][32];

  const int tid = threadIdx.x;
  const int lane = tid & 63;
  const int wv = tid >> 6;
  const int wr = wv >> 1, wc = wv & 1;
  const int bm = blockIdx.x, bn = blockIdx.y;

  const int arow = tid >> 1;
  const int acol = (tid & 1) << 4;
  const float* aptr = x + (size_t)(bm * 128 + arow) * K_DIM + acol;
  const int fA = (arow >> 1) & 3;
  const int ac0 = (tid & 1) * 2;
  const int aw0 = ((ac0) ^ fA) * 8;
  const int aw1 = ((ac0 + 1) ^ fA) * 8;

  const int brow0 = wv * 32 + (lane >> 2);
  const int bsrcc = (lane & 3) ^ ((lane >> 3) & 3);
  const unsigned short* bptr0 = wq + (size_t)(bn * 128 + brow0) * K_DIM + bsrcc * 8;
  const unsigned short* bptr1 = bptr0 + (size_t)16 * K_DIM;

  v4f acc[4][4];
  #pragma unroll
  for (int i = 0; i < 4; i++)
    #pragma unroll
    for (int j = 0; j < 4; j++) acc[i][j] = (v4f)(0.0f);

  const int frow = lane & 15;
  const int fkc = lane >> 4;
  const int fsw = (fkc ^ ((frow >> 1) & 3)) * 8;

  float4 areg[4];
  #pragma unroll
  for (int j = 0; j < 4; j++) areg[j] = *(const float4*)(aptr + j * 4);

  {
    const float* f = (const float*)areg;
    union { v8s v; unsigned short u[8]; } cv0, cv1;
    #pragma unroll
    for (int i = 0; i < 8; i++) { cv0.u[i] = f2bf(f[i]); cv1.u[i] = f2bf(f[i + 8]); }
    *(v8s*)&As[0][arow][aw0] = cv0.v;
    *(v8s*)&As[0][arow][aw1] = cv1.v;
    gload16(bptr0, &Bs[0][wv * 32][0]);
    gload16(bptr1, &Bs[0][wv * 32 + 16][0]);
  }
  #pragma unroll
  for (int j = 0; j < 4; j++) areg[j] = *(const float4*)(aptr + 32 + j * 4);
  __syncthreads();

  for (int kt = 0; kt < K_DIM / 32; ++kt) {
    const int cur = kt & 1, nxt = cur ^ 1;
    if (kt + 1 < K_DIM / 32) {
      const float* f = (const float*)areg;
      union { v8s v; unsigned short u[8]; } cv0, cv1;
      #pragma unroll
      for (int i = 0; i < 8; i++) { cv0.u[i] = f2bf(f[i]); cv1.u[i] = f2bf(f[i + 8]); }
      *(v8s*)&As[nxt][arow][aw0] = cv0.v;
      *(v8s*)&As[nxt][arow][aw1] = cv1.v;
      gload16(bptr0 + (size_t)(kt + 1) * 32, &Bs[nxt][wv * 32][0]);
      gload16(bptr1 + (size_t)(kt + 1) * 32, &Bs[nxt][wv * 32 + 16][0]);
      if (kt + 2 < K_DIM / 32) {
        const float* ap = aptr + (kt + 2) * 32;
        #pragma unroll
        for (int j = 0; j < 4; j++) areg[j] = *(const float4*)(ap + j * 4);
      }
    }
    v8s af[4], bf[4];
    #pragma unroll
    for (int m = 0; m < 4; m++)
      af[m] = *(const v8s*)&As[cur][wr * 64 + m * 16 + frow][fsw];
    #pragma unroll
    for (int n = 0; n < 4; n++)
      bf[n] = *(const v8s*)&Bs[cur][wc * 64 + n * 16 + frow][fsw];
    #pragma unroll
    for (int m = 0; m < 4; m++)
      #pragma unroll
      for (int n = 0; n < 4; n++)
        acc[m][n] = __builtin_amdgcn_mfma_f32_16x16x32_bf16(af[m], bf[n], acc[m][n], 0, 0, 0);
    __syncthreads();
  }

  const int colbase = bn * 128 + wc * 64;
  const int rowbase = bm * 128 + wr * 64;
  #pragma unroll
  for (int n = 0; n < 4; n++) {
    const int col = colbase + n * 16 + (lane & 15);
    const float bv = bias[col];
    #pragma unroll
    for (int m = 0; m < 4; m++) {
      const int row0 = rowbase + m * 16 + (lane >> 4) * 4;
      #pragma unroll
      for (int r = 0; r < 4; r++)
        out[(size_t)(row0 + r) * N_DIM + col] = acc[m][n][r] + bv;
    }
  }
}

extern "C" void kernel_launch(void* const* d_in, const int* in_sizes, int n_in,
                              void* d_out, int out_size, void* d_ws, size_t ws_size,
                              hipStream_t stream) {
  const float* x = (const float*)d_in[0];      // 16384 x 1024
  const float* wt = (const float*)d_in[1];     // 1024 x 1024 (n, m)
  const float* bias = (const float*)d_in[2];   // 1024
  float* out = (float*)d_out;                  // 16384 x 1024

  float* part = (float*)d_ws;
  float* mm = part + 512;
  unsigned short* wqbuf = (unsigned short*)((char*)d_ws + 4096);
  const size_t need = 4096 + 2ull * 1024 * 1024;

  wminmax_part<<<256, 256, 0, stream>>>(wt, part);
  wminmax_final<<<1, 256, 0, stream>>>(part, mm);
  quant_kernel<<<1024, 256, 0, stream>>>(wt, mm, wqbuf);

  if (ws_size >= need) {
    dim3 grid(M_DIM / 256, N_DIM / 256);
    gemm_fused<<<grid, 512, 0, stream>>>(x, wqbuf, bias, out);
  } else {
    dim3 grid(M_DIM / 128, N_DIM / 128);
    gemm_kernel<<<grid, 256, 0, stream>>>(x, wqbuf, bias, out);
  }
}

// Round 19
// 62.079 us; speedup vs baseline: 1.2393x; 1.0274x over previous
//
#include <hip/hip_runtime.h>
#include <hip/hip_bf16.h>

#define M_DIM 16384
#define N_DIM 1024
#define K_DIM 1024

typedef short v8s __attribute__((ext_vector_type(8)));
typedef float v4f __attribute__((ext_vector_type(4)));
typedef unsigned v2u __attribute__((ext_vector_type(2)));

__device__ __forceinline__ unsigned short f2bf(float f) {
  unsigned u = __float_as_uint(f);
  unsigned r = (u + 0x7FFFu + ((u >> 16) & 1u)) >> 16;
  return (unsigned short)r;
}

// RTNE f32->bf16 via compiler intrinsic: pairs into v_cvt_pk_bf16_f32
// (proven round 17; identical rounding to the bit-twiddle).
__device__ __forceinline__ unsigned short f2bf_hw(float f) {
  __hip_bfloat16 h = __float2bfloat16(f);
  return *reinterpret_cast<unsigned short*>(&h);
}

__device__ __forceinline__ void gload16(const void* g, void* l) {
  __builtin_amdgcn_global_load_lds(
      (const __attribute__((address_space(1))) void*)g,
      (__attribute__((address_space(3))) void*)l, 16, 0, 0);
}

// inline-asm ds_read_b128: invisible to SIInsertWaitcnts.
#define DSR(dst, addr, off) \
  asm volatile("ds_read_b128 %0, %1 offset:" off : "=v"(dst) : "v"(addr))

// ---------- stage 1: weight max/min partials (float4-vectorized) ----------
__global__ void wminmax_part(const float* __restrict__ w, float* __restrict__ part) {
  int tid = blockIdx.x * 256 + threadIdx.x;
  float mx = -3.402823466e38f, mn = 3.402823466e38f;
  for (int i = tid; i < N_DIM * K_DIM / 4; i += 256 * 256) {
    float4 v = *(const float4*)(w + i * 4);
    mx = fmaxf(fmaxf(mx, fmaxf(v.x, v.y)), fmaxf(v.z, v.w));
    mn = fminf(fminf(mn, fminf(v.x, v.y)), fminf(v.z, v.w));
  }
  #pragma unroll
  for (int o = 32; o > 0; o >>= 1) {
    mx = fmaxf(mx, __shfl_down(mx, o));
    mn = fminf(mn, __shfl_down(mn, o));
  }
  __shared__ float smx[4], smn[4];
  int lane = threadIdx.x & 63, wv = threadIdx.x >> 6;
  if (lane == 0) { smx[wv] = mx; smn[wv] = mn; }
  __syncthreads();
  if (threadIdx.x == 0) {
    mx = fmaxf(fmaxf(smx[0], smx[1]), fmaxf(smx[2], smx[3]));
    mn = fminf(fminf(smn[0], smn[1]), fminf(smn[2], smn[3]));
    part[blockIdx.x] = mx;
    part[256 + blockIdx.x] = mn;
  }
}

// ---------- stage 2 (merged): final reduce (redundant per block, L2-hit)
// + fake-quant. Saves one launch + dependency bubble vs 3-kernel chain.
__global__ void quant_kernel(const float* __restrict__ w, const float* __restrict__ part,
                             unsigned short* __restrict__ wq) {
  const int t = threadIdx.x;
  // each block reduces the 512 partials itself (2 floats/thread, exact)
  float mx = part[t & 255];
  float mn = part[256 + (t & 255)];
  #pragma unroll
  for (int o = 32; o > 0; o >>= 1) {
    mx = fmaxf(mx, __shfl_down(mx, o));
    mn = fminf(mn, __shfl_down(mn, o));
  }
  __shared__ float smx[4], smn[4];
  __shared__ float sab[2];
  const int lane = t & 63, wvv = t >> 6;
  if (lane == 0) { smx[wvv] = mx; smn[wvv] = mn; }
  __syncthreads();
  if (t == 0) {
    mx = fmaxf(fmaxf(smx[0], smx[1]), fmaxf(smx[2], smx[3]));
    mn = fminf(fminf(smn[0], smn[1]), fminf(smn[2], smn[3]));
    sab[0] = mx - mn;   // alpha
    sab[1] = mn;        // beta
  }
  __syncthreads();
  const float alpha = sab[0], beta = sab[1];
  int i = (blockIdx.x * 256 + t) * 4;
  float4 v = *(const float4*)(w + i);
  float f[4] = {v.x, v.y, v.z, v.w};
  ushort4 o;
  unsigned short ov[4];
  #pragma unroll
  for (int j = 0; j < 4; j++) {
    // exact reference op sequence (fp32 divisions, rint = round-half-even)
    float s = (f[j] - beta) / alpha;
    float R = rintf(15.0f * s) / 15.0f;
    float q = alpha * R + beta;
    if (f[j] == 0.0f) q = 0.0f;
    ov[j] = f2bf(q);
  }
  o.x = ov[0]; o.y = ov[1]; o.z = ov[2]; o.w = ov[3];
  *(ushort4*)(wq + i) = o;
}

// ---------- stage 3: fused 256x256 GEMM (round-18 proven) ----------
// This round's tweak: PH1 lgkmcnt(4) — MFMA doesn't wait for the CVTW
// ds_writes (issued after the 4 reads; in-order completion); post-MFMA
// lgkmcnt(0) drains them (free by then) before the end-of-phase barrier,
// preserving the cross-wave write->read ordering argument.
__global__ __launch_bounds__(512, 2) void gemm_fused(
    const float* __restrict__ x, const unsigned short* __restrict__ wq,
    const float* __restrict__ bias, float* __restrict__ out) {
  __shared__ __attribute__((aligned(16))) unsigned short As[2][256][32];  // 32KB
  __shared__ __attribute__((aligned(16))) unsigned short Bs[4][256][32];  // 64KB

  const int tid = threadIdx.x;
  const int lane = tid & 63;
  const int wv = tid >> 6;     // 0..7
  const int wr = wv >> 2;      // 0..1  (M half: 128 rows)
  const int wc = wv & 3;       // 0..3  (N quarter: 64 cols)
  const int bm = blockIdx.x;   // 0..63
  const int bn = blockIdx.y;   // 0..3

  const int srow = wv * 32 + (lane >> 2);
  const int ssw = ((lane & 3) ^ ((lane >> 3) & 3)) * 8;
  const unsigned short* bS = wq + (size_t)(bn * 256 + srow) * K_DIM + ssw;

  const float* aF = x + (size_t)(bm * 256 + wv * 32 + (lane >> 3)) * K_DIM + (lane & 7) * 4;

  const int frow = lane & 15;
  const int fsw = ((lane >> 4) ^ ((frow >> 1) & 3)) * 8;
  const unsigned ldsA0 =
      (unsigned)(unsigned long long)(__attribute__((address_space(3))) unsigned short*)&As[0][0][0];
  const unsigned ldsB0 =
      (unsigned)(unsigned long long)(__attribute__((address_space(3))) unsigned short*)&Bs[0][0][0];
  const unsigned aLane = ldsA0 + (unsigned)((wr * 128 + frow) * 32 + fsw) * 2u;
  const unsigned bLane = ldsB0 + (unsigned)((wc * 64 + frow) * 32 + fsw) * 2u;

  const unsigned wA = ldsA0 +
      (unsigned)((wv * 32 + (lane >> 3)) * 64 +
                 ((((lane & 7) >> 1) ^ ((lane >> 4) & 3)) * 16) + ((lane & 7) & 1) * 8);

  v4f acc[8][4];
  #pragma unroll
  for (int m = 0; m < 8; m++)
    #pragma unroll
    for (int n = 0; n < 4; n++) acc[m][n] = (v4f)(0.0f);

  v8s af[4], bf[4];
  float4 ra0[4], ra1[4];

#define RA_LOAD(RA_, H2_) do { \
    _Pragma("unroll") \
    for (int j_ = 0; j_ < 4; j_++) \
      RA_[j_] = *(const float4*)(aF + (size_t)(H2_) * 32 + j_ * 8 * K_DIM); \
  } while (0)

#define CVTW(RA_, SL_) do { \
    _Pragma("unroll") \
    for (int j_ = 0; j_ < 4; j_++) { \
      v2u p_; \
      p_.x = (unsigned)f2bf_hw(RA_[j_].x) | ((unsigned)f2bf_hw(RA_[j_].y) << 16); \
      p_.y = (unsigned)f2bf_hw(RA_[j_].z) | ((unsigned)f2bf_hw(RA_[j_].w) << 16); \
      asm volatile("ds_write_b64 %0, %1" \
                   :: "v"(wA + (SL_) * 16384u + j_ * 512u), "v"(p_) : "memory"); \
    } \
  } while (0)

#define STAGE_B(H_, SL_) do { \
    gload16(bS + (size_t)(H_) * 32, &Bs[SL_][wv * 32][0]); \
    gload16(bS + (size_t)(H_) * 32 + 16 * K_DIM, &Bs[SL_][wv * 32 + 16][0]); \
  } while (0)

#define MM16(MH_) do { \
    _Pragma("unroll") \
    for (int i_ = 0; i_ < 4; i_++) \
      _Pragma("unroll") \
      for (int n_ = 0; n_ < 4; n_++) \
        acc[(MH_) * 4 + i_][n_] = __builtin_amdgcn_mfma_f32_16x16x32_bf16( \
            af[i_], bf[n_], acc[(MH_) * 4 + i_], 0, 0, 0); \
  } while (0)
#undef MM16
#define MM16(MH_) do { \
    _Pragma("unroll") \
    for (int i_ = 0; i_ < 4; i_++) \
      _Pragma("unroll") \
      for (int n_ = 0; n_ < 4; n_++) \
        acc[(MH_) * 4 + i_][n_] = __builtin_amdgcn_mfma_f32_16x16x32_bf16( \
            af[i_], bf[n_], acc[(MH_) * 4 + i_][n_], 0, 0, 0); \
  } while (0)

#define PH0(H_, AS_, BS_, RALD_, STG_) do { \
    const unsigned aP = aLane + (AS_) * 16384u; \
    const unsigned bP = bLane + (BS_) * 16384u; \
    DSR(af[0], aP, "0");    DSR(af[1], aP, "1024"); \
    DSR(af[2], aP, "2048"); DSR(af[3], aP, "3072"); \
    DSR(bf[0], bP, "0");    DSR(bf[1], bP, "1024"); \
    DSR(bf[2], bP, "2048"); DSR(bf[3], bP, "3072"); \
    if (STG_) RA_LOAD(RALD_, (H_) + 2); \
    __builtin_amdgcn_s_barrier(); \
    asm volatile("s_waitcnt lgkmcnt(0)" ::: "memory"); \
    __builtin_amdgcn_sched_barrier(0); \
    __builtin_amdgcn_s_setprio(1); \
    MM16(0); \
    __builtin_amdgcn_s_setprio(0); \
    __builtin_amdgcn_s_barrier(); \
  } while (0)

  // PH1: reads af x4 FIRST, then CVTW writes x4 (in-order completion ->
  // lgkmcnt(4) = all 4 reads done, writes may still fly under the MFMAs).
#define PH1(H_, AS_, BW_, RACV_, STG_, CVT_, GATE_) do { \
    const unsigned aP = aLane + (AS_) * 16384u + 4096u; \
    DSR(af[0], aP, "0");    DSR(af[1], aP, "1024"); \
    DSR(af[2], aP, "2048"); DSR(af[3], aP, "3072"); \
    if (CVT_) CVTW(RACV_, (AS_) ^ 1); \
    if (STG_) STAGE_B((H_) + 2, BW_); \
    __builtin_amdgcn_s_barrier(); \
    if (CVT_) { asm volatile("s_waitcnt lgkmcnt(4)" ::: "memory"); } \
    else      { asm volatile("s_waitcnt lgkmcnt(0)" ::: "memory"); } \
    __builtin_amdgcn_sched_barrier(0); \
    __builtin_amdgcn_s_setprio(1); \
    MM16(1); \
    __builtin_amdgcn_s_setprio(0); \
    asm volatile("s_waitcnt lgkmcnt(0)" ::: "memory"); \
    asm volatile("s_waitcnt vmcnt(" GATE_ ")" ::: "memory"); \
    __builtin_amdgcn_s_barrier(); \
  } while (0)

#define KHALF(H_, AS_, BS_, BW_, RALD_, RACV_, STG_, CVT_, GATE_) do { \
    PH0(H_, AS_, BS_, RALD_, STG_); \
    PH1(H_, AS_, BW_, RACV_, STG_, CVT_, GATE_); \
  } while (0)

  // ---- prologue ----
  RA_LOAD(ra0, 0);
  RA_LOAD(ra1, 1);
  STAGE_B(0, 0);
  STAGE_B(1, 1);
  CVTW(ra0, 0);
  asm volatile("s_waitcnt vmcnt(2)" ::: "memory");
  asm volatile("s_waitcnt lgkmcnt(0)" ::: "memory");
  __builtin_amdgcn_s_barrier();

  // ---- main: 7 x 4 K-halves (h = 0..27) ----
  #pragma unroll 1
  for (int kh = 0; kh < 28; kh += 4) {
    KHALF(kh + 0, 0, 0, 2, ra0, ra1, 1, 1, "6");
    KHALF(kh + 1, 1, 1, 3, ra1, ra0, 1, 1, "6");
    KHALF(kh + 2, 0, 2, 0, ra0, ra1, 1, 1, "6");
    KHALF(kh + 3, 1, 3, 1, ra1, ra0, 1, 1, "6");
  }
  // ---- tail ----
  KHALF(28, 0, 0, 2, ra0, ra1, 1, 1, "6");
  KHALF(29, 1, 1, 3, ra1, ra0, 1, 1, "6");
  KHALF(30, 0, 2, 0, ra0, ra1, 0, 1, "0");
  KHALF(31, 1, 3, 0, ra1, ra0, 0, 0, "0");

#undef KHALF
#undef PH0
#undef PH1
#undef MM16
#undef STAGE_B
#undef CVTW
#undef RA_LOAD

  // ---- epilogue: LDS-transposed fully-coalesced C-write (round-18) ----
  {
    float* eb = (float*)(&As[0][0][0]) + wv * (16 * 64);
    const int colbase = bn * 256 + wc * 64;
    const int rowbase = bm * 256 + wr * 128;
    float bv[4];
    #pragma unroll
    for (int n = 0; n < 4; n++) bv[n] = bias[colbase + n * 16 + (lane & 15)];
    const int er = lane >> 4;
    const int ec = lane & 15;
    const int rr = lane >> 2;
    const int q  = lane & 3;
    #pragma unroll
    for (int m = 0; m < 8; m++) {
      #pragma unroll
      for (int n = 0; n < 4; n++) {
        #pragma unroll
        for (int r = 0; r < 4; r++) {
          const int R = er * 4 + r;
          const int cn = n * 16 + ec;
          const int g = cn >> 2;
          eb[R * 64 + ((g ^ (R & 15)) << 2) + (cn & 3)] = acc[m][n][r] + bv[n];
        }
      }
      float* orow = out + (size_t)(rowbase + m * 16 + rr) * N_DIM + colbase;
      #pragma unroll
      for (int j = 0; j < 4; j++) {
        const int g = j * 4 + q;
        v4f v = *(v4f*)&eb[rr * 64 + ((g ^ (rr & 15)) << 2)];
        *(v4f*)&orow[j * 16 + q * 4] = v;
      }
    }
  }
}

// ---------- fallback (ws too small): round-2 proven kernel ----------
__global__ __launch_bounds__(256) void gemm_kernel(
    const float* __restrict__ x, const unsigned short* __restrict__ wq,
    const float* __restrict__ bias, float* __restrict__ out) {
  __shared__ __attribute__((aligned(16))) unsigned short As[2][128][32];
  __shared__ __attribute__((aligned(16))) unsigned short Bs[2][128][32];

  const int tid = threadIdx.x;
  const int lane = tid & 63;
  const int wv = tid >> 6;
  const int wr = wv >> 1, wc = wv & 1;
  const int bm = blockIdx.x, bn = blockIdx.y;

  const int arow = tid >> 1;
  const int acol = (tid & 1) << 4;
  const float* aptr = x + (size_t)(bm * 128 + arow) * K_DIM + acol;
  const int fA = (arow >> 1) & 3;
  const int ac0 = (tid & 1) * 2;
  const int aw0 = ((ac0) ^ fA) * 8;
  const int aw1 = ((ac0 + 1) ^ fA) * 8;

  const int brow0 = wv * 32 + (lane >> 2);
  const int bsrcc = (lane & 3) ^ ((lane >> 3) & 3);
  const unsigned short* bptr0 = wq + (size_t)(bn * 128 + brow0) * K_DIM + bsrcc * 8;
  const unsigned short* bptr1 = bptr0 + (size_t)16 * K_DIM;

  v4f acc[4][4];
  #pragma unroll
  for (int i = 0; i < 4; i++)
    #pragma unroll
    for (int j = 0; j < 4; j++) acc[i][j] = (v4f)(0.0f);

  const int frow = lane & 15;
  const int fkc = lane >> 4;
  const int fsw = (fkc ^ ((frow >> 1) & 3)) * 8;

  float4 areg[4];
  #pragma unroll
  for (int j = 0; j < 4; j++) areg[j] = *(const float4*)(aptr + j * 4);

  {
    const float* f = (const float*)areg;
    union { v8s v; unsigned short u[8]; } cv0, cv1;
    #pragma unroll
    for (int i = 0; i < 8; i++) { cv0.u[i] = f2bf(f[i]); cv1.u[i] = f2bf(f[i + 8]); }
    *(v8s*)&As[0][arow][aw0] = cv0.v;
    *(v8s*)&As[0][arow][aw1] = cv1.v;
    gload16(bptr0, &Bs[0][wv * 32][0]);
    gload16(bptr1, &Bs[0][wv * 32 + 16][0]);
  }
  #pragma unroll
  for (int j = 0; j < 4; j++) areg[j] = *(const float4*)(aptr + 32 + j * 4);
  __syncthreads();

  for (int kt = 0; kt < K_DIM / 32; ++kt) {
    const int cur = kt & 1, nxt = cur ^ 1;
    if (kt + 1 < K_DIM / 32) {
      const float* f = (const float*)areg;
      union { v8s v; unsigned short u[8]; } cv0, cv1;
      #pragma unroll
      for (int i = 0; i < 8; i++) { cv0.u[i] = f2bf(f[i]); cv1.u[i] = f2bf(f[i + 8]); }
      *(v8s*)&As[nxt][arow][aw0] = cv0.v;
      *(v8s*)&As[nxt][arow][aw1] = cv1.v;
      gload16(bptr0 + (size_t)(kt + 1) * 32, &Bs[nxt][wv * 32][0]);
      gload16(bptr1 + (size_t)(kt + 1) * 32, &Bs[nxt][wv * 32 + 16][0]);
      if (kt + 2 < K_DIM / 32) {
        const float* ap = aptr + (kt + 2) * 32;
        #pragma unroll
        for (int j = 0; j < 4; j++) areg[j] = *(const float4*)(ap + j * 4);
      }
    }
    v8s af[4], bf[4];
    #pragma unroll
    for (int m = 0; m < 4; m++)
      af[m] = *(const v8s*)&As[cur][wr * 64 + m * 16 + frow][fsw];
    #pragma unroll
    for (int n = 0; n < 4; n++)
      bf[n] = *(const v8s*)&Bs[cur][wc * 64 + n * 16 + frow][fsw];
    #pragma unroll
    for (int m = 0; m < 4; m++)
      #pragma unroll
      for (int n = 0; n < 4; n++)
        acc[m][n] = __builtin_amdgcn_mfma_f32_16x16x32_bf16(af[m], bf[n], acc[m][n], 0, 0, 0);
    __syncthreads();
  }

  const int colbase = bn * 128 + wc * 64;
  const int rowbase = bm * 128 + wr * 64;
  #pragma unroll
  for (int n = 0; n < 4; n++) {
    const int col = colbase + n * 16 + (lane & 15);
    const float bv = bias[col];
    #pragma unroll
    for (int m = 0; m < 4; m++) {
      const int row0 = rowbase + m * 16 + (lane >> 4) * 4;
      #pragma unroll
      for (int r = 0; r < 4; r++)
        out[(size_t)(row0 + r) * N_DIM + col] = acc[m][n][r] + bv;
    }
  }
}

extern "C" void kernel_launch(void* const* d_in, const int* in_sizes, int n_in,
                              void* d_out, int out_size, void* d_ws, size_t ws_size,
                              hipStream_t stream) {
  const float* x = (const float*)d_in[0];      // 16384 x 1024
  const float* wt = (const float*)d_in[1];     // 1024 x 1024 (n, m)
  const float* bias = (const float*)d_in[2];   // 1024
  float* out = (float*)d_out;                  // 16384 x 1024

  float* part = (float*)d_ws;
  unsigned short* wqbuf = (unsigned short*)((char*)d_ws + 4096);
  const size_t need = 4096 + 2ull * 1024 * 1024;

  wminmax_part<<<256, 256, 0, stream>>>(wt, part);
  quant_kernel<<<1024, 256, 0, stream>>>(wt, part, wqbuf);

  if (ws_size >= need) {
    dim3 grid(M_DIM / 256, N_DIM / 256);
    gemm_fused<<<grid, 512, 0, stream>>>(x, wqbuf, bias, out);
  } else {
    dim3 grid(M_DIM / 128, N_DIM / 128);
    gemm_kernel<<<grid, 256, 0, stream>>>(x, wqbuf, bias, out);
  }
}

// Round 20
// 56.395 us; speedup vs baseline: 1.3642x; 1.1008x over previous
//
#include <hip/hip_runtime.h>
#include <hip/hip_bf16.h>

#define M_DIM 16384
#define N_DIM 1024
#define K_DIM 1024

typedef short v8s __attribute__((ext_vector_type(8)));
typedef float v4f __attribute__((ext_vector_type(4)));
typedef unsigned v2u __attribute__((ext_vector_type(2)));

__device__ __forceinline__ unsigned short f2bf(float f) {
  unsigned u = __float_as_uint(f);
  unsigned r = (u + 0x7FFFu + ((u >> 16) & 1u)) >> 16;
  return (unsigned short)r;
}

// RTNE f32->bf16 via compiler intrinsic: pairs into v_cvt_pk_bf16_f32
// (proven round 17; identical rounding to the bit-twiddle).
__device__ __forceinline__ unsigned short f2bf_hw(float f) {
  __hip_bfloat16 h = __float2bfloat16(f);
  return *reinterpret_cast<unsigned short*>(&h);
}

__device__ __forceinline__ void gload16(const void* g, void* l) {
  __builtin_amdgcn_global_load_lds(
      (const __attribute__((address_space(1))) void*)g,
      (__attribute__((address_space(3))) void*)l, 16, 0, 0);
}

// inline-asm ds_read_b128: invisible to SIInsertWaitcnts.
#define DSR(dst, addr, off) \
  asm volatile("ds_read_b128 %0, %1 offset:" off : "=v"(dst) : "v"(addr))

// ---------- stage 1: weight max/min partials (float4-vectorized) ----------
__global__ void wminmax_part(const float* __restrict__ w, float* __restrict__ part) {
  int tid = blockIdx.x * 256 + threadIdx.x;
  float mx = -3.402823466e38f, mn = 3.402823466e38f;
  for (int i = tid; i < N_DIM * K_DIM / 4; i += 256 * 256) {
    float4 v = *(const float4*)(w + i * 4);
    mx = fmaxf(fmaxf(mx, fmaxf(v.x, v.y)), fmaxf(v.z, v.w));
    mn = fminf(fminf(mn, fminf(v.x, v.y)), fminf(v.z, v.w));
  }
  #pragma unroll
  for (int o = 32; o > 0; o >>= 1) {
    mx = fmaxf(mx, __shfl_down(mx, o));
    mn = fminf(mn, __shfl_down(mn, o));
  }
  __shared__ float smx[4], smn[4];
  int lane = threadIdx.x & 63, wv = threadIdx.x >> 6;
  if (lane == 0) { smx[wv] = mx; smn[wv] = mn; }
  __syncthreads();
  if (threadIdx.x == 0) {
    mx = fmaxf(fmaxf(smx[0], smx[1]), fmaxf(smx[2], smx[3]));
    mn = fminf(fminf(smn[0], smn[1]), fminf(smn[2], smn[3]));
    part[blockIdx.x] = mx;
    part[256 + blockIdx.x] = mn;
  }
}

// ---------- stage 2 (merged): final reduce + fake-quant (round-19 proven) ----------
__global__ void quant_kernel(const float* __restrict__ w, const float* __restrict__ part,
                             unsigned short* __restrict__ wq) {
  const int t = threadIdx.x;
  float mx = part[t & 255];
  float mn = part[256 + (t & 255)];
  #pragma unroll
  for (int o = 32; o > 0; o >>= 1) {
    mx = fmaxf(mx, __shfl_down(mx, o));
    mn = fminf(mn, __shfl_down(mn, o));
  }
  __shared__ float smx[4], smn[4];
  __shared__ float sab[2];
  const int lane = t & 63, wvv = t >> 6;
  if (lane == 0) { smx[wvv] = mx; smn[wvv] = mn; }
  __syncthreads();
  if (t == 0) {
    mx = fmaxf(fmaxf(smx[0], smx[1]), fmaxf(smx[2], smx[3]));
    mn = fminf(fminf(smn[0], smn[1]), fminf(smn[2], smn[3]));
    sab[0] = mx - mn;
    sab[1] = mn;
  }
  __syncthreads();
  const float alpha = sab[0], beta = sab[1];
  int i = (blockIdx.x * 256 + t) * 4;
  float4 v = *(const float4*)(w + i);
  float f[4] = {v.x, v.y, v.z, v.w};
  ushort4 o;
  unsigned short ov[4];
  #pragma unroll
  for (int j = 0; j < 4; j++) {
    float s = (f[j] - beta) / alpha;
    float R = rintf(15.0f * s) / 15.0f;
    float q = alpha * R + beta;
    if (f[j] == 0.0f) q = 0.0f;
    ov[j] = f2bf(q);
  }
  o.x = ov[0]; o.y = ov[1]; o.z = ov[2]; o.w = ov[3];
  *(ushort4*)(wq + i) = o;
}

// ---------- stage 3: fused 256x256 GEMM — ONE barrier per K-half.
// Hazard proof for removed barriers: every LDS slot's readers finish (counted
// lgkm before their own MFMA) at least one retained end-of-K-half barrier
// before that slot's next writer issues: B 4-slot ring has 2 intervening
// barriers; A ping-pong has 1 (readers of slot s at K-half h-1 complete
// before barrier(h-1); CVTW(h) writes s after it, drained by post-MFMA
// lgkm(0) before barrier(h); next readers at h+1 after barrier(h)).
__global__ __launch_bounds__(512, 2) void gemm_fused(
    const float* __restrict__ x, const unsigned short* __restrict__ wq,
    const float* __restrict__ bias, float* __restrict__ out) {
  __shared__ __attribute__((aligned(16))) unsigned short As[2][256][32];  // 32KB
  __shared__ __attribute__((aligned(16))) unsigned short Bs[4][256][32];  // 64KB

  const int tid = threadIdx.x;
  const int lane = tid & 63;
  const int wv = tid >> 6;     // 0..7
  const int wr = wv >> 2;      // 0..1  (M half: 128 rows)
  const int wc = wv & 3;       // 0..3  (N quarter: 64 cols)
  const int bm = blockIdx.x;   // 0..63
  const int bn = blockIdx.y;   // 0..3

  const int srow = wv * 32 + (lane >> 2);
  const int ssw = ((lane & 3) ^ ((lane >> 3) & 3)) * 8;
  const unsigned short* bS = wq + (size_t)(bn * 256 + srow) * K_DIM + ssw;

  const float* aF = x + (size_t)(bm * 256 + wv * 32 + (lane >> 3)) * K_DIM + (lane & 7) * 4;

  const int frow = lane & 15;
  const int fsw = ((lane >> 4) ^ ((frow >> 1) & 3)) * 8;
  const unsigned ldsA0 =
      (unsigned)(unsigned long long)(__attribute__((address_space(3))) unsigned short*)&As[0][0][0];
  const unsigned ldsB0 =
      (unsigned)(unsigned long long)(__attribute__((address_space(3))) unsigned short*)&Bs[0][0][0];
  const unsigned aLane = ldsA0 + (unsigned)((wr * 128 + frow) * 32 + fsw) * 2u;
  const unsigned bLane = ldsB0 + (unsigned)((wc * 64 + frow) * 32 + fsw) * 2u;

  const unsigned wA = ldsA0 +
      (unsigned)((wv * 32 + (lane >> 3)) * 64 +
                 ((((lane & 7) >> 1) ^ ((lane >> 4) & 3)) * 16) + ((lane & 7) & 1) * 8);

  v4f acc[8][4];
  #pragma unroll
  for (int m = 0; m < 8; m++)
    #pragma unroll
    for (int n = 0; n < 4; n++) acc[m][n] = (v4f)(0.0f);

  v8s af[4], bf[4];
  float4 ra0[4], ra1[4];

#define RA_LOAD(RA_, H2_) do { \
    _Pragma("unroll") \
    for (int j_ = 0; j_ < 4; j_++) \
      RA_[j_] = *(const float4*)(aF + (size_t)(H2_) * 32 + j_ * 8 * K_DIM); \
  } while (0)

#define CVTW(RA_, SL_) do { \
    _Pragma("unroll") \
    for (int j_ = 0; j_ < 4; j_++) { \
      v2u p_; \
      p_.x = (unsigned)f2bf_hw(RA_[j_].x) | ((unsigned)f2bf_hw(RA_[j_].y) << 16); \
      p_.y = (unsigned)f2bf_hw(RA_[j_].z) | ((unsigned)f2bf_hw(RA_[j_].w) << 16); \
      asm volatile("ds_write_b64 %0, %1" \
                   :: "v"(wA + (SL_) * 16384u + j_ * 512u), "v"(p_) : "memory"); \
    } \
  } while (0)

#define STAGE_B(H_, SL_) do { \
    gload16(bS + (size_t)(H_) * 32, &Bs[SL_][wv * 32][0]); \
    gload16(bS + (size_t)(H_) * 32 + 16 * K_DIM, &Bs[SL_][wv * 32 + 16][0]); \
  } while (0)

#define MM16(MH_) do { \
    _Pragma("unroll") \
    for (int i_ = 0; i_ < 4; i_++) \
      _Pragma("unroll") \
      for (int n_ = 0; n_ < 4; n_++) \
        acc[(MH_) * 4 + i_][n_] = __builtin_amdgcn_mfma_f32_16x16x32_bf16( \
            af[i_], bf[n_], acc[(MH_) * 4 + i_][n_], 0, 0, 0); \
  } while (0)

  // PH0: no barriers — reads from slots published >=1 barrier ago; own-wave
  // lgkm(0) orders reads->MFMA.
#define PH0(H_, AS_, BS_, RALD_, STG_) do { \
    const unsigned aP = aLane + (AS_) * 16384u; \
    const unsigned bP = bLane + (BS_) * 16384u; \
    DSR(af[0], aP, "0");    DSR(af[1], aP, "1024"); \
    DSR(af[2], aP, "2048"); DSR(af[3], aP, "3072"); \
    DSR(bf[0], bP, "0");    DSR(bf[1], bP, "1024"); \
    DSR(bf[2], bP, "2048"); DSR(bf[3], bP, "3072"); \
    if (STG_) RA_LOAD(RALD_, (H_) + 2); \
    asm volatile("s_waitcnt lgkmcnt(0)" ::: "memory"); \
    __builtin_amdgcn_sched_barrier(0); \
    __builtin_amdgcn_s_setprio(1); \
    MM16(0); \
    __builtin_amdgcn_s_setprio(0); \
  } while (0)

  // PH1: reads af x4 FIRST, then CVTW writes, then B stage; lgkm(4) releases
  // MFMA when the 4 reads land; post-MFMA lgkm(0) drains CVTW writes and
  // vmcnt gate verifies h+1 staging landed; the ONE barrier publishes.
#define PH1(H_, AS_, BW_, RACV_, STG_, CVT_, GATE_) do { \
    const unsigned aP = aLane + (AS_) * 16384u + 4096u; \
    DSR(af[0], aP, "0");    DSR(af[1], aP, "1024"); \
    DSR(af[2], aP, "2048"); DSR(af[3], aP, "3072"); \
    if (CVT_) CVTW(RACV_, (AS_) ^ 1); \
    if (STG_) STAGE_B((H_) + 2, BW_); \
    if (CVT_) { asm volatile("s_waitcnt lgkmcnt(4)" ::: "memory"); } \
    else      { asm volatile("s_waitcnt lgkmcnt(0)" ::: "memory"); } \
    __builtin_amdgcn_sched_barrier(0); \
    __builtin_amdgcn_s_setprio(1); \
    MM16(1); \
    __builtin_amdgcn_s_setprio(0); \
    asm volatile("s_waitcnt lgkmcnt(0)" ::: "memory"); \
    asm volatile("s_waitcnt vmcnt(" GATE_ ")" ::: "memory"); \
    __builtin_amdgcn_s_barrier(); \
  } while (0)

#define KHALF(H_, AS_, BS_, BW_, RALD_, RACV_, STG_, CVT_, GATE_) do { \
    PH0(H_, AS_, BS_, RALD_, STG_); \
    PH1(H_, AS_, BW_, RACV_, STG_, CVT_, GATE_); \
  } while (0)

  // ---- prologue ----
  RA_LOAD(ra0, 0);
  RA_LOAD(ra1, 1);
  STAGE_B(0, 0);
  STAGE_B(1, 1);
  CVTW(ra0, 0);
  asm volatile("s_waitcnt vmcnt(2)" ::: "memory");
  asm volatile("s_waitcnt lgkmcnt(0)" ::: "memory");
  __builtin_amdgcn_s_barrier();

  // ---- main: 7 x 4 K-halves (h = 0..27) ----
  #pragma unroll 1
  for (int kh = 0; kh < 28; kh += 4) {
    KHALF(kh + 0, 0, 0, 2, ra0, ra1, 1, 1, "6");
    KHALF(kh + 1, 1, 1, 3, ra1, ra0, 1, 1, "6");
    KHALF(kh + 2, 0, 2, 0, ra0, ra1, 1, 1, "6");
    KHALF(kh + 3, 1, 3, 1, ra1, ra0, 1, 1, "6");
  }
  // ---- tail ----
  KHALF(28, 0, 0, 2, ra0, ra1, 1, 1, "6");
  KHALF(29, 1, 1, 3, ra1, ra0, 1, 1, "6");
  KHALF(30, 0, 2, 0, ra0, ra1, 0, 1, "0");
  KHALF(31, 1, 3, 0, ra1, ra0, 0, 0, "0");

#undef KHALF
#undef PH0
#undef PH1
#undef MM16
#undef STAGE_B
#undef CVTW
#undef RA_LOAD

  // ---- epilogue: LDS-transposed fully-coalesced C-write (round-18 proven).
  // Final K-half ended with a barrier; all LDS traffic drained.
  {
    float* eb = (float*)(&As[0][0][0]) + wv * (16 * 64);
    const int colbase = bn * 256 + wc * 64;
    const int rowbase = bm * 256 + wr * 128;
    float bv[4];
    #pragma unroll
    for (int n = 0; n < 4; n++) bv[n] = bias[colbase + n * 16 + (lane & 15)];
    const int er = lane >> 4;
    const int ec = lane & 15;
    const int rr = lane >> 2;
    const int q  = lane & 3;
    #pragma unroll
    for (int m = 0; m < 8; m++) {
      #pragma unroll
      for (int n = 0; n < 4; n++) {
        #pragma unroll
        for (int r = 0; r < 4; r++) {
          const int R = er * 4 + r;
          const int cn = n * 16 + ec;
          const int g = cn >> 2;
          eb[R * 64 + ((g ^ (R & 15)) << 2) + (cn & 3)] = acc[m][n][r] + bv[n];
        }
      }
      float* orow = out + (size_t)(rowbase + m * 16 + rr) * N_DIM + colbase;
      #pragma unroll
      for (int j = 0; j < 4; j++) {
        const int g = j * 4 + q;
        v4f v = *(v4f*)&eb[rr * 64 + ((g ^ (rr & 15)) << 2)];
        *(v4f*)&orow[j * 16 + q * 4] = v;
      }
    }
  }
}

// ---------- fallback (ws too small): round-2 proven kernel ----------
__global__ __launch_bounds__(256) void gemm_kernel(
    const float* __restrict__ x, const unsigned short* __restrict__ wq,
    const float* __restrict__ bias, float* __restrict__ out) {
  __shared__ __attribute__((aligned(16))) unsigned short As[2][128][32];
  __shared__ __attribute__((aligned(16))) unsigned short Bs[2][128][32];

  const int tid = threadIdx.x;
  const int lane = tid & 63;
  const int wv = tid >> 6;
  const int wr = wv >> 1, wc = wv & 1;
  const int bm = blockIdx.x, bn = blockIdx.y;

  const int arow = tid >> 1;
  const int acol = (tid & 1) << 4;
  const float* aptr = x + (size_t)(bm * 128 + arow) * K_DIM + acol;
  const int fA = (arow >> 1) & 3;
  const int ac0 = (tid & 1) * 2;
  const int aw0 = ((ac0) ^ fA) * 8;
  const int aw1 = ((ac0 + 1) ^ fA) * 8;

  const int brow0 = wv * 32 + (lane >> 2);
  const int bsrcc = (lane & 3) ^ ((lane >> 3) & 3);
  const unsigned short* bptr0 = wq + (size_t)(bn * 128 + brow0) * K_DIM + bsrcc * 8;
  const unsigned short* bptr1 = bptr0 + (size_t)16 * K_DIM;

  v4f acc[4][4];
  #pragma unroll
  for (int i = 0; i < 4; i++)
    #pragma unroll
    for (int j = 0; j < 4; j++) acc[i][j] = (v4f)(0.0f);

  const int frow = lane & 15;
  const int fkc = lane >> 4;
  const int fsw = (fkc ^ ((frow >> 1) & 3)) * 8;

  float4 areg[4];
  #pragma unroll
  for (int j = 0; j < 4; j++) areg[j] = *(const float4*)(aptr + j * 4);

  {
    const float* f = (const float*)areg;
    union { v8s v; unsigned short u[8]; } cv0, cv1;
    #pragma unroll
    for (int i = 0; i < 8; i++) { cv0.u[i] = f2bf(f[i]); cv1.u[i] = f2bf(f[i + 8]); }
    *(v8s*)&As[0][arow][aw0] = cv0.v;
    *(v8s*)&As[0][arow][aw1] = cv1.v;
    gload16(bptr0, &Bs[0][wv * 32][0]);
    gload16(bptr1, &Bs[0][wv * 32 + 16][0]);
  }
  #pragma unroll
  for (int j = 0; j < 4; j++) areg[j] = *(const float4*)(aptr + 32 + j * 4);
  __syncthreads();

  for (int kt = 0; kt < K_DIM / 32; ++kt) {
    const int cur = kt & 1, nxt = cur ^ 1;
    if (kt + 1 < K_DIM / 32) {
      const float* f = (const float*)areg;
      union { v8s v; unsigned short u[8]; } cv0, cv1;
      #pragma unroll
      for (int i = 0; i < 8; i++) { cv0.u[i] = f2bf(f[i]); cv1.u[i] = f2bf(f[i + 8]); }
      *(v8s*)&As[nxt][arow][aw0] = cv0.v;
      *(v8s*)&As[nxt][arow][aw1] = cv1.v;
      gload16(bptr0 + (size_t)(kt + 1) * 32, &Bs[nxt][wv * 32][0]);
      gload16(bptr1 + (size_t)(kt + 1) * 32, &Bs[nxt][wv * 32 + 16][0]);
      if (kt + 2 < K_DIM / 32) {
        const float* ap = aptr + (kt + 2) * 32;
        #pragma unroll
        for (int j = 0; j < 4; j++) areg[j] = *(const float4*)(ap + j * 4);
      }
    }
    v8s af[4], bf[4];
    #pragma unroll
    for (int m = 0; m < 4; m++)
      af[m] = *(const v8s*)&As[cur][wr * 64 + m * 16 + frow][fsw];
    #pragma unroll
    for (int n = 0; n < 4; n++)
      bf[n] = *(const v8s*)&Bs[cur][wc * 64 + n * 16 + frow][fsw];
    #pragma unroll
    for (int m = 0; m < 4; m++)
      #pragma unroll
      for (int n = 0; n < 4; n++)
        acc[m][n] = __builtin_amdgcn_mfma_f32_16x16x32_bf16(af[m], bf[n], acc[m][n], 0, 0, 0);
    __syncthreads();
  }

  const int colbase = bn * 128 + wc * 64;
  const int rowbase = bm * 128 + wr * 64;
  #pragma unroll
  for (int n = 0; n < 4; n++) {
    const int col = colbase + n * 16 + (lane & 15);
    const float bv = bias[col];
    #pragma unroll
    for (int m = 0; m < 4; m++) {
      const int row0 = rowbase + m * 16 + (lane >> 4) * 4;
      #pragma unroll
      for (int r = 0; r < 4; r++)
        out[(size_t)(row0 + r) * N_DIM + col] = acc[m][n][r] + bv;
    }
  }
}

extern "C" void kernel_launch(void* const* d_in, const int* in_sizes, int n_in,
                              void* d_out, int out_size, void* d_ws, size_t ws_size,
                              hipStream_t stream) {
  const float* x = (const float*)d_in[0];      // 16384 x 1024
  const float* wt = (const float*)d_in[1];     // 1024 x 1024 (n, m)
  const float* bias = (const float*)d_in[2];   // 1024
  float* out = (float*)d_out;                  // 16384 x 1024

  float* part = (float*)d_ws;
  unsigned short* wqbuf = (unsigned short*)((char*)d_ws + 4096);
  const size_t need = 4096 + 2ull * 1024 * 1024;

  wminmax_part<<<256, 256, 0, stream>>>(wt, part);
  quant_kernel<<<1024, 256, 0, stream>>>(wt, part, wqbuf);

  if (ws_size >= need) {
    dim3 grid(M_DIM / 256, N_DIM / 256);
    gemm_fused<<<grid, 512, 0, stream>>>(x, wqbuf, bias, out);
  } else {
    dim3 grid(M_DIM / 128, N_DIM / 128);
    gemm_kernel<<<grid, 256, 0, stream>>>(x, wqbuf, bias, out);
  }
}